// Round 9
// baseline (1009.917 us; speedup 1.0000x reference)
//
#include <hip/hip_runtime.h>
#include <hip/hip_bf16.h>

// Problem constants (fixed-shape problem)
#define NN 262144      // nodes = 4096 graphs * 64
#define EE 2097152     // edges
#define BB 4096        // graphs
constexpr int INMLP = 6144;
constexpr int HID = 2048;
constexpr int HID4 = 512;
constexpr int OUTF = 256;
constexpr int NSL = 16;            // edge slices
constexpr int ESL = EE / NSL;      // 131072 edges per slice
constexpr int RNODES = 32768;      // nodes per range (8 ranges)

typedef short s16x8 __attribute__((ext_vector_type(8)));   // 8 bf16 in 4 VGPRs
typedef short s16x4 __attribute__((ext_vector_type(4)));
typedef float f32x4 __attribute__((ext_vector_type(4)));

__device__ __forceinline__ float lrelu(float v) { return v >= 0.f ? v : 0.01f * v; }
__device__ __forceinline__ float bf2f(short s) {
    unsigned int u = ((unsigned int)(unsigned short)s) << 16;
    return __builtin_bit_cast(float, u);
}
__device__ __forceinline__ short f2bf(float f) {   // RNE
    unsigned int u = __builtin_bit_cast(unsigned int, f);
    u = (u + 0x7fff + ((u >> 16) & 1)) >> 16;
    return (short)u;
}
// async global->LDS, 16B per lane. LDS dest = wave-uniform base + lane*16.
__device__ __forceinline__ void async16(const void* g, void* l) {
    __builtin_amdgcn_global_load_lds((__attribute__((address_space(1))) void*)g,
                                     (__attribute__((address_space(3))) void*)l, 16, 0, 0);
}

// ---------------- degree counting via LDS histograms (no global atomics) ----------------
// Grid 256 = type(2) x range(8) x slice(16). Each block: 64KB LDS histogram of packed-u16
// counters for its 32768-node range; streams its 131072-edge slice; LDS atomicAdd (CU-local).
// dst-type blocks also capture each edge's rank within (node, slice) -> rankpack16.
__global__ __launch_bounds__(256) void hist_count(const int* __restrict__ dst, const int* __restrict__ src,
                                                  unsigned* __restrict__ part_din, unsigned* __restrict__ part_dout,
                                                  unsigned short* __restrict__ rankpack16) {
    __shared__ unsigned hist[RNODES / 2];   // 65536 B
    const int S = blockIdx.x & 15;
    const int R = (blockIdx.x >> 4) & 7;
    const int T = blockIdx.x >> 7;          // 0 = din(dst)+rank, 1 = dout(src)
    for (int i = threadIdx.x; i < RNODES / 2; i += 256) hist[i] = 0;
    __syncthreads();
    const int* idxarr = T ? src : dst;
    const int e0 = S * ESL;
    for (int e = e0 + threadIdx.x; e < e0 + ESL; e += 256) {
        int idx = idxarr[e];
        if ((idx >> 15) == R) {
            int local = idx & (RNODES - 1);
            unsigned old = atomicAdd(&hist[local >> 1], 1u << ((local & 1) * 16));
            if (T == 0) {
                unsigned rank = (old >> ((local & 1) * 16)) & 0xffffu;
                rankpack16[e] = (unsigned short)((S << 11) | rank);   // rank < 2048 (max deg ~35)
            }
        }
    }
    __syncthreads();
    unsigned* dp = (T ? part_dout : part_din) + (size_t)S * (NN / 2) + R * (RNODES / 2);
    for (int i = threadIdx.x; i < RNODES / 2; i += 256) dp[i] = hist[i];
}

// ---------------- reduce slices: degrees, rsqrt factors, per-(slice,node) base offsets ----------------
// One thread per packed word (2 nodes). repbase stored as packed u16 pairs, same layout.
__global__ __launch_bounds__(256) void deg_reduce(const unsigned* __restrict__ part_din,
                                                  const unsigned* __restrict__ part_dout,
                                                  unsigned* __restrict__ repbase_w,   // [NSL][NN/2] packed u16
                                                  float* __restrict__ ro, float* __restrict__ ri,
                                                  int* __restrict__ din) {
    int i = blockIdx.x * 256 + threadIdx.x;    // word index over NN/2
    unsigned runl = 0, runh = 0, dl = 0, dh = 0;
#pragma unroll
    for (int S = 0; S < NSL; S++) {
        repbase_w[(size_t)S * (NN / 2) + i] = (runl & 0xffffu) | (runh << 16);
        unsigned w = part_din[(size_t)S * (NN / 2) + i];
        runl += w & 0xffffu; runh += w >> 16;
        unsigned w2 = part_dout[(size_t)S * (NN / 2) + i];
        dl += w2 & 0xffffu; dh += w2 >> 16;
    }
    int n0 = 2 * i, n1 = 2 * i + 1;
    din[n0] = (int)runl; din[n1] = (int)runh;
    ro[n0] = rsqrtf((float)(dl < 1u ? 1u : dl));
    ro[n1] = rsqrtf((float)(dh < 1u ? 1u : dh));
    ri[n0] = rsqrtf((float)(runl < 1u ? 1u : runl));
    ri[n1] = rsqrtf((float)(runh < 1u ? 1u : runh));
}

// ---------------- scan (exclusive prefix over din counts -> CSR offsets) ----------------
__global__ __launch_bounds__(256) void scanA(const int* __restrict__ cnt, int* __restrict__ blks) {
    __shared__ int s[256];
    int t = threadIdx.x;
    int i0 = blockIdx.x * 1024 + t * 4;
    int ts = cnt[i0] + cnt[i0 + 1] + cnt[i0 + 2] + cnt[i0 + 3];
    s[t] = ts; __syncthreads();
    for (int d = 128; d > 0; d >>= 1) { if (t < d) s[t] += s[t + d]; __syncthreads(); }
    if (t == 0) blks[blockIdx.x] = s[0];
}

__global__ __launch_bounds__(256) void scanB(int* __restrict__ blks, int* __restrict__ offN) {
    __shared__ int s[256];
    int t = threadIdx.x;
    int v = blks[t]; s[t] = v; __syncthreads();
    for (int d = 1; d < 256; d <<= 1) {
        int x = (t >= d) ? s[t - d] : 0; __syncthreads();
        s[t] += x; __syncthreads();
    }
    blks[t] = s[t] - v;            // exclusive
    if (t == 255) *offN = s[255];  // total = EE
}

__global__ __launch_bounds__(256) void scanC(const int* __restrict__ cnt, const int* __restrict__ blkoff,
                                             int* __restrict__ off) {
    __shared__ int s[256];
    int t = threadIdx.x;
    int i0 = blockIdx.x * 1024 + t * 4;
    int v0 = cnt[i0], v1 = cnt[i0 + 1], v2 = cnt[i0 + 2], v3 = cnt[i0 + 3];
    int ts = v0 + v1 + v2 + v3;
    s[t] = ts; __syncthreads();
    for (int d = 1; d < 256; d <<= 1) {
        int x = (t >= d) ? s[t - d] : 0; __syncthreads();
        s[t] += x; __syncthreads();
    }
    int base = blkoff[blockIdx.x] + (s[t] - ts);
    off[i0] = base; off[i0 + 1] = base + v0; off[i0 + 2] = base + v0 + v1; off[i0 + 3] = base + v0 + v1 + v2;
}

// ---------------- fill CSR: atomic-free scatter via (slice, rank) + repbase ----------------
// edge record = int2 { src, bf32(ew * ro[src]) }  (ro folded in by linearity)
__global__ __launch_bounds__(256) void fill_csr(const int* __restrict__ src, const int* __restrict__ dst,
                                                const float* __restrict__ ew, const float* __restrict__ ro,
                                                const int* __restrict__ off,
                                                const unsigned short* __restrict__ repbase16,  // [NSL][NN]
                                                const unsigned short* __restrict__ rankpack16,
                                                int2* __restrict__ edg) {
    int e = blockIdx.x * 256 + threadIdx.x;
    int d = dst[e];
    int s = src[e];
    unsigned pk = rankpack16[e];
    int S = pk >> 11, rank = pk & 2047;
    int p = off[d] + (int)repbase16[(size_t)S * NN + d] + rank;
    edg[p] = make_int2(s, __builtin_bit_cast(int, ew[e] * ro[s]));
}

// ---------------- x fp32 -> bf16 ----------------
__global__ __launch_bounds__(256) void cvt_x(const float* __restrict__ X, short* __restrict__ Xb) {
    int i = (blockIdx.x * 256 + threadIdx.x) * 4;
    float4 v = *(const float4*)(X + i);
    s16x4 o = { f2bf(v.x), f2bf(v.y), f2bf(v.z), f2bf(v.w) };
    *(s16x4*)(Xb + i) = o;
}

// ---------------- gather 64 dims, edge-parallel: 8 edges x 8 chunks of 8 dims ----------------
__global__ __launch_bounds__(256) void gather64(const short* __restrict__ Xb, const int* __restrict__ offs,
                                                const int2* __restrict__ edg, short* __restrict__ Out) {
    const int lane = threadIdx.x & 63;
    const int e = lane >> 3, c = lane & 7;
    int node = blockIdx.x * 4 + (threadIdx.x >> 6);
    node = __builtin_amdgcn_readfirstlane(node);
    const int s0 = offs[node], s1 = offs[node + 1];
    float acc[8] = {};
    for (int j0 = s0; j0 < s1; j0 += 8) {
        int j = j0 + e;
        bool ok = j < s1;
        int2 pe = edg[ok ? j : s0];
        int s = pe.x;
        float w = ok ? __builtin_bit_cast(float, pe.y) : 0.f;
        s16x8 v = *(const s16x8*)&Xb[(size_t)s * 64 + c * 8];
#pragma unroll
        for (int k = 0; k < 8; k++) acc[k] = fmaf(w, bf2f(v[k]), acc[k]);
    }
#pragma unroll
    for (int off = 8; off <= 32; off <<= 1)
#pragma unroll
        for (int k = 0; k < 8; k++) acc[k] += __shfl_xor(acc[k], off);
    if (e == 0) {
        s16x8 o;
#pragma unroll
        for (int k = 0; k < 8; k++) o[k] = f2bf(acc[k]);
        *(s16x8*)&Out[(size_t)node * 64 + c * 8] = o;
    }
}

// ---------------- conv1 + GraphNorm1 fused: MFMA 262144x128x64, block = 128 rows = 2 graphs ----------------
__global__ __launch_bounds__(256) void conv1_gn(const short* __restrict__ A, const short* __restrict__ BT,
                                                const float* __restrict__ ri,
                                                const float* __restrict__ alpha, const float* __restrict__ gamma,
                                                const float* __restrict__ beta, short* __restrict__ Outp) {
    __shared__ short As[128][72];
    __shared__ short Bs[128][72];
    __shared__ float sscale[2][128], sshift[2][128];
    const int t = threadIdx.x;
    const int bm = blockIdx.x * 128;
    const int wave = t >> 6, lane = t & 63;
    const int wm = (wave & 1) * 64, wn = (wave >> 1) * 64;
    const int g = wave & 1;
    const int m16 = lane & 15, quad = lane >> 4;
#pragma unroll
    for (int i = 0; i < 4; i++) {
        int idx = t + 256 * i;
        int rr = idx >> 3, kk = (idx & 7) * 8;
        *(s16x8*)&As[rr][kk] = *(const s16x8*)&A[(size_t)(bm + rr) * 64 + kk];
        *(s16x8*)&Bs[rr][kk] = *(const s16x8*)&BT[(size_t)rr * 64 + kk];
    }
    __syncthreads();
    f32x4 acc[4][4] = {};
#pragma unroll
    for (int kc = 0; kc < 2; kc++) {
        s16x8 af[4], bfr[4];
#pragma unroll
        for (int mt = 0; mt < 4; mt++) af[mt] = *(const s16x8*)&As[wm + mt * 16 + m16][kc * 32 + quad * 8];
#pragma unroll
        for (int nt = 0; nt < 4; nt++) bfr[nt] = *(const s16x8*)&Bs[wn + nt * 16 + m16][kc * 32 + quad * 8];
#pragma unroll
        for (int mt = 0; mt < 4; mt++)
#pragma unroll
            for (int nt = 0; nt < 4; nt++)
                acc[mt][nt] = __builtin_amdgcn_mfma_f32_16x16x32_bf16(af[mt], bfr[nt], acc[mt][nt], 0, 0, 0);
    }
    // transform in place: v = lrelu(h1 * ri[row])
#pragma unroll
    for (int mt = 0; mt < 4; mt++)
#pragma unroll
        for (int r4 = 0; r4 < 4; r4++) {
            float rv = ri[bm + wm + mt * 16 + quad * 4 + r4];
#pragma unroll
            for (int nt = 0; nt < 4; nt++)
                acc[mt][nt][r4] = lrelu(acc[mt][nt][r4] * rv);
        }
    // per-channel stats: sum over mt,r4 (in-register) + quad (shfl_xor 16,32)
#pragma unroll
    for (int nt = 0; nt < 4; nt++) {
        float s1 = 0.f, s2 = 0.f;
#pragma unroll
        for (int mt = 0; mt < 4; mt++)
#pragma unroll
            for (int r4 = 0; r4 < 4; r4++) { float v = acc[mt][nt][r4]; s1 += v; s2 += v * v; }
        s1 += __shfl_xor(s1, 16); s1 += __shfl_xor(s1, 32);
        s2 += __shfl_xor(s2, 16); s2 += __shfl_xor(s2, 32);
        if (quad == 0) {
            int ch = wn + nt * 16 + m16;
            float m = s1 * (1.f / 64.f);
            float a = alpha[ch];
            float var = s2 * (1.f / 64.f) - m * m * a * (2.f - a);   // E[(v-am)^2]
            float sc = gamma[ch] * rsqrtf(var + 1e-5f);
            sscale[g][ch] = sc;
            sshift[g][ch] = beta[ch] - sc * a * m;
        }
    }
    __syncthreads();
#pragma unroll
    for (int nt = 0; nt < 4; nt++) {
        int ch = wn + nt * 16 + m16;
        float sc = sscale[g][ch], sh = sshift[g][ch];
#pragma unroll
        for (int mt = 0; mt < 4; mt++)
#pragma unroll
            for (int r4 = 0; r4 < 4; r4++) {
                int row = bm + wm + mt * 16 + quad * 4 + r4;
                Outp[(size_t)row * 128 + ch] = f2bf(sc * acc[mt][nt][r4] + sh);
            }
    }
}

// ---------------- conv2: MFMA GEMM 262144x96x128, A=gn1 bf16, BT=W2T bf16 (96x128), out h2 bf16 ----------------
__global__ __launch_bounds__(256) void conv2_mfma(const short* __restrict__ A, const short* __restrict__ BT,
                                                  short* __restrict__ H) {
    __shared__ short As[128][136];   // 128 k + 8 pad
    __shared__ short Bs[96][136];
    const int t = threadIdx.x;
    const int bm = blockIdx.x * 128;
    const int wave = t >> 6, lane = t & 63;
    const int wm = (wave & 1) * 64, wn = (wave >> 1) * 48;
    const int m16 = lane & 15, quad = lane >> 4;
#pragma unroll
    for (int i = 0; i < 8; i++) {
        int idx = t + 256 * i;
        int rr = idx >> 4, kk = (idx & 15) * 8;
        *(s16x8*)&As[rr][kk] = *(const s16x8*)&A[(size_t)(bm + rr) * 128 + kk];
    }
#pragma unroll
    for (int i = 0; i < 6; i++) {
        int idx = t + 256 * i;
        int nr = idx >> 4, kk = (idx & 15) * 8;
        *(s16x8*)&Bs[nr][kk] = *(const s16x8*)&BT[(size_t)nr * 128 + kk];
    }
    __syncthreads();
    f32x4 acc[4][3] = {};
#pragma unroll
    for (int kc = 0; kc < 4; kc++) {
        s16x8 af[4], bfr[3];
#pragma unroll
        for (int mt = 0; mt < 4; mt++) af[mt] = *(const s16x8*)&As[wm + mt * 16 + m16][kc * 32 + quad * 8];
#pragma unroll
        for (int nt = 0; nt < 3; nt++) bfr[nt] = *(const s16x8*)&Bs[wn + nt * 16 + m16][kc * 32 + quad * 8];
#pragma unroll
        for (int mt = 0; mt < 4; mt++)
#pragma unroll
            for (int nt = 0; nt < 3; nt++)
                acc[mt][nt] = __builtin_amdgcn_mfma_f32_16x16x32_bf16(af[mt], bfr[nt], acc[mt][nt], 0, 0, 0);
    }
#pragma unroll
    for (int mt = 0; mt < 4; mt++)
#pragma unroll
        for (int r4 = 0; r4 < 4; r4++) {
            int row = bm + wm + mt * 16 + quad * 4 + r4;
#pragma unroll
            for (int nt = 0; nt < 3; nt++)
                H[(size_t)row * 96 + wn + nt * 16 + m16] = f2bf(acc[mt][nt][r4]);
        }
}

// ---------------- gather 96 dims + GraphNorm2 fused: block = 1 graph (64 nodes) ----------------
__global__ __launch_bounds__(256) void gather_gn2(const short* __restrict__ H, const int* __restrict__ offs,
                                                  const int2* __restrict__ edg,
                                                  const float* __restrict__ ri,
                                                  const float* __restrict__ alpha, const float* __restrict__ gamma,
                                                  const float* __restrict__ beta, short* __restrict__ Outp) {
    __shared__ float sm[64 * 96];
    __shared__ float sscale[96], sshift[96];
    const int g = blockIdx.x;
    const int wave = threadIdx.x >> 6, lane = threadIdx.x & 63;
    const int e = lane >> 4, c = lane & 15;
    for (int nl = wave * 16; nl < wave * 16 + 16; nl++) {
        const int node = g * 64 + nl;
        const int s0 = offs[node], s1 = offs[node + 1];
        float acc[6] = {};
        for (int j0 = s0; j0 < s1; j0 += 4) {
            int j = j0 + e;
            bool ok = j < s1;
            int2 pe = edg[ok ? j : s0];
            int s = pe.x;
            float w = ok ? __builtin_bit_cast(float, pe.y) : 0.f;
            const unsigned int* hp = (const unsigned int*)(H + (size_t)s * 96 + c * 6);
            unsigned int u0 = hp[0], u1 = hp[1], u2 = hp[2];
            acc[0] = fmaf(w, bf2f((short)(u0 & 0xffff)), acc[0]);
            acc[1] = fmaf(w, bf2f((short)(u0 >> 16)), acc[1]);
            acc[2] = fmaf(w, bf2f((short)(u1 & 0xffff)), acc[2]);
            acc[3] = fmaf(w, bf2f((short)(u1 >> 16)), acc[3]);
            acc[4] = fmaf(w, bf2f((short)(u2 & 0xffff)), acc[4]);
            acc[5] = fmaf(w, bf2f((short)(u2 >> 16)), acc[5]);
        }
#pragma unroll
        for (int off = 16; off <= 32; off <<= 1)
#pragma unroll
            for (int k = 0; k < 6; k++) acc[k] += __shfl_xor(acc[k], off);
        if (e == 0) {
            float rv = ri[node];
#pragma unroll
            for (int k = 0; k < 6; k++) sm[nl * 96 + c * 6 + k] = lrelu(acc[k] * rv);
        }
    }
    __syncthreads();
    if (threadIdx.x < 96) {
        int cch = threadIdx.x;
        float s1v = 0.f, s2v = 0.f;
#pragma unroll 4
        for (int i = 0; i < 64; i++) { float v = sm[i * 96 + cch]; s1v += v; s2v += v * v; }
        float m = s1v * (1.f / 64.f);
        float a = alpha[cch];
        float var = s2v * (1.f / 64.f) - m * m * a * (2.f - a);
        float sc = gamma[cch] * rsqrtf(var + 1e-5f);
        sscale[cch] = sc;
        sshift[cch] = beta[cch] - sc * a * m;
    }
    __syncthreads();
#pragma unroll
    for (int i = 0; i < 6; i++) {
        int q = threadIdx.x + 256 * i;       // 0..1535
        int nl = q / 24, cq = (q % 24) * 4;
        s16x4 o;
#pragma unroll
        for (int k = 0; k < 4; k++) o[k] = f2bf(sscale[cq + k] * sm[nl * 96 + cq + k] + sshift[cq + k]);
        *(s16x4*)&Outp[(size_t)(g * 64 + nl) * 96 + cq] = o;
    }
}

// ---------------- W fp32 (R x Cc) -> WT bf16 (Cc x R), tiled transpose+convert ----------------
__global__ __launch_bounds__(256) void transp_cvt(const float* __restrict__ W, short* __restrict__ WT,
                                                  int R, int Cc) {
    __shared__ short tile[32][33];
    const int bc = blockIdx.x * 32;   // col of W
    const int br = blockIdx.y * 32;   // row of W
    const int tx = threadIdx.x & 31, ty = threadIdx.x >> 5;   // 32 x 8
#pragma unroll
    for (int i = 0; i < 32; i += 8)
        tile[ty + i][tx] = f2bf(W[(size_t)(br + ty + i) * Cc + bc + tx]);
    __syncthreads();
#pragma unroll
    for (int i = 0; i < 32; i += 8)
        WT[(size_t)(bc + ty + i) * R + br + tx] = tile[tx][ty + i];
}

// ---------------- MLP1: bf16 MFMA GEMM 4096x2048x6144 (global_load_lds BK=64, XOR-swizzled LDS) ----------------
__global__ __launch_bounds__(256) void mlp1_mfma(const short* __restrict__ A, const short* __restrict__ BT,
                                                 float* __restrict__ C) {
    constexpr int K = INMLP, Nn = HID;
    __shared__ short As[128 * 64];
    __shared__ short Bs[128 * 64];
    const int t = threadIdx.x;
    const int bm = blockIdx.x * 128, bn = blockIdx.y * 128;
    const int wave = t >> 6, lane = t & 63;
    const int wm = (wave & 1) * 64, wn = (wave >> 1) * 64;
    const int m16 = lane & 15, quad = lane >> 4;
    const int lrow = lane >> 3, lcol = lane & 7;
    const int scol = lcol ^ (lrow & 7);        // swizzled fetch chunk
    const int xkey = m16 & 7;                  // read-side unswizzle key
    f32x4 acc[4][4] = {};
    for (int k0 = 0; k0 < K; k0 += 64) {
#pragma unroll
        for (int j = 0; j < 4; j++) {
            const int rbase = 32 * wave + 8 * j;   // wave-uniform
            async16(&A[(size_t)(bm + rbase + lrow) * K + k0 + scol * 8], &As[rbase * 64]);
            async16(&BT[(size_t)(bn + rbase + lrow) * K + k0 + scol * 8], &Bs[rbase * 64]);
        }
        __syncthreads();
#pragma unroll
        for (int kc = 0; kc < 2; kc++) {
            s16x8 af[4], bfr[4];
#pragma unroll
            for (int mt = 0; mt < 4; mt++)
                af[mt] = *(const s16x8*)&As[(wm + mt * 16 + m16) * 64 + (((kc * 4 + quad) ^ xkey)) * 8];
#pragma unroll
            for (int nt = 0; nt < 4; nt++)
                bfr[nt] = *(const s16x8*)&Bs[(wn + nt * 16 + m16) * 64 + (((kc * 4 + quad) ^ xkey)) * 8];
#pragma unroll
            for (int mt = 0; mt < 4; mt++)
#pragma unroll
                for (int nt = 0; nt < 4; nt++)
                    acc[mt][nt] = __builtin_amdgcn_mfma_f32_16x16x32_bf16(af[mt], bfr[nt], acc[mt][nt], 0, 0, 0);
        }
        __syncthreads();
    }
#pragma unroll
    for (int mt = 0; mt < 4; mt++)
#pragma unroll
        for (int nt = 0; nt < 4; nt++)
#pragma unroll
            for (int r4 = 0; r4 < 4; r4++) {
                int row = bm + wm + mt * 16 + quad * 4 + r4;
                int col = bn + wn + nt * 16 + m16;
                C[(size_t)row * Nn + col] = lrelu(acc[mt][nt][r4]);
            }
}

// ---------------- generic MFMA GEMM: A fp32 (converted on stage), BT bf16, C fp32 ----------------
template <bool LEAKY>
__global__ __launch_bounds__(256) void mfma_gemm_af32(const float* __restrict__ A, const short* __restrict__ BT,
                                                      float* __restrict__ C, int M, int Nn, int K) {
    __shared__ short As[64][40];
    __shared__ short Bs[64][40];
    const int t = threadIdx.x;
    const int bm = blockIdx.x * 64, bn = blockIdx.y * 64;
    const int wave = t >> 6, lane = t & 63;
    const int wm = (wave & 1) * 32, wn = (wave >> 1) * 32;
    const int m16 = lane & 15, quad = lane >> 4;
    const int rr = t >> 2, kk = (t & 3) * 8;
    f32x4 acc[2][2] = {};
    for (int k0 = 0; k0 < K; k0 += 32) {
        const float* ap = &A[(size_t)(bm + rr) * K + k0 + kk];
        float4 v0 = *(const float4*)ap;
        float4 v1 = *(const float4*)(ap + 4);
        s16x8 a8;
        a8[0] = f2bf(v0.x); a8[1] = f2bf(v0.y); a8[2] = f2bf(v0.z); a8[3] = f2bf(v0.w);
        a8[4] = f2bf(v1.x); a8[5] = f2bf(v1.y); a8[6] = f2bf(v1.z); a8[7] = f2bf(v1.w);
        *(s16x8*)&As[rr][kk] = a8;
        *(s16x8*)&Bs[rr][kk] = *(const s16x8*)&BT[(size_t)(bn + rr) * K + k0 + kk];
        __syncthreads();
        s16x8 af[2], bfr[2];
#pragma unroll
        for (int mt = 0; mt < 2; mt++) af[mt] = *(const s16x8*)&As[wm + mt * 16 + m16][quad * 8];
#pragma unroll
        for (int nt = 0; nt < 2; nt++) bfr[nt] = *(const s16x8*)&Bs[wn + nt * 16 + m16][quad * 8];
#pragma unroll
        for (int mt = 0; mt < 2; mt++)
#pragma unroll
            for (int nt = 0; nt < 2; nt++)
                acc[mt][nt] = __builtin_amdgcn_mfma_f32_16x16x32_bf16(af[mt], bfr[nt], acc[mt][nt], 0, 0, 0);
        __syncthreads();
    }
#pragma unroll
    for (int mt = 0; mt < 2; mt++)
#pragma unroll
        for (int nt = 0; nt < 2; nt++)
#pragma unroll
            for (int r4 = 0; r4 < 4; r4++) {
                int row = bm + wm + mt * 16 + quad * 4 + r4;
                int col = bn + wn + nt * 16 + m16;
                float v = acc[mt][nt][r4];
                if (LEAKY) v = lrelu(v);
                C[(size_t)row * Nn + col] = v;
            }
}

// ---------------- per-row InstanceNorm (in place, fp32) ----------------
template <int NC>
__global__ __launch_bounds__(256) void rownorm(float* __restrict__ Y) {
    float* p = Y + (size_t)blockIdx.x * NC;
    float s1 = 0.f, s2 = 0.f;
    for (int c = threadIdx.x; c < NC; c += 256) { float v = p[c]; s1 += v; s2 += v * v; }
#pragma unroll
    for (int o = 32; o > 0; o >>= 1) { s1 += __shfl_down(s1, o); s2 += __shfl_down(s2, o); }
    __shared__ float w1[4], w2[4];
    if ((threadIdx.x & 63) == 0) { w1[threadIdx.x >> 6] = s1; w2[threadIdx.x >> 6] = s2; }
    __syncthreads();
    s1 = w1[0] + w1[1] + w1[2] + w1[3];
    s2 = w2[0] + w2[1] + w2[2] + w2[3];
    float m = s1 * (1.f / NC);
    float inv = rsqrtf(s2 * (1.f / NC) - m * m + 1e-5f);
    for (int c = threadIdx.x; c < NC; c += 256) p[c] = (p[c] - m) * inv;
}

extern "C" void kernel_launch(void* const* d_in, const int* in_sizes, int n_in,
                              void* d_out, int out_size, void* d_ws, size_t ws_size,
                              hipStream_t stream) {
    const float* x    = (const float*)d_in[0];
    const float* ew   = (const float*)d_in[1];
    const int*   src  = (const int*)d_in[2];
    const int*   dst  = (const int*)d_in[3];
    const float* W1   = (const float*)d_in[4];
    const float* W2   = (const float*)d_in[5];
    const float* a1   = (const float*)d_in[6];
    const float* g1   = (const float*)d_in[7];
    const float* b1   = (const float*)d_in[8];
    const float* a2   = (const float*)d_in[9];
    const float* g2   = (const float*)d_in[10];
    const float* b2   = (const float*)d_in[11];
    const float* Win  = (const float*)d_in[12];
    const float* Whid = (const float*)d_in[13];
    const float* Wcls = (const float*)d_in[14];
    float* out = (float*)d_out;

    // ---- workspace layout (~141 MB fixed) ----
    float* ro   = (float*)d_ws;                    // NN
    float* ri   = ro + NN;                         // NN
    int*   din  = (int*)(ri + NN);                 // NN (deg_in for scan)
    int*   offs = din + NN;                        // NN+4
    int*   blks = offs + NN + 4;                   // 256
    short* w1t  = (short*)(blks + 256);            // 128*64 bf16
    short* w2t  = w1t + 128 * 64;                  // 96*128 bf16
    int2*  edg  = (int2*)(((size_t)(w2t + 96 * 128) + 15) & ~(size_t)15);   // EE int2 (src, ew*ro)
    short* Abf  = (short*)(edg + EE);              // NN*128 bf16 region
    short* Bbf  = Abf + (size_t)NN * 128;          // NN*128 bf16 region
    short* xbf  = Abf;                             // NN*64
    short* aggx = Abf + (size_t)NN * 64;           // NN*64
    // graph-build temps overlaid into Abf region (dead until cvt_x): 28 MB
    unsigned*       part_din   = (unsigned*)Abf;                       // NSL * NN/2 words (8 MB)
    unsigned*       part_dout  = part_din + (size_t)NSL * (NN / 2);    // 8 MB
    unsigned*       repbase_w  = part_dout + (size_t)NSL * (NN / 2);   // NSL * NN/2 words (8 MB)
    unsigned short* rankpack16 = (unsigned short*)(repbase_w + (size_t)NSL * (NN / 2));  // EE u16 (4 MB)
    // overlays into Abf region after gather_gn2 (h2 dead):
    short* WinT = Abf;                                                  // 2048*6144 bf16 = 25165824 B
    float* D    = (float*)((char*)Abf + 25165824);                      // 4096*2048 fp32 = 33554432 B
    float* Y2   = (float*)((char*)Abf + 25165824 + 33554432);           // 4096*512 fp32  =  8388608 B
    // overlays into Bbf region after mlp1_mfma consumes it:
    short* WhidT = Bbf;                            // 512*2048 bf16
    short* WclsT = WhidT + (size_t)HID4 * HID;     // 256*512 bf16

    // 1) degrees + per-edge ranks via LDS histograms (no global atomics, no memset)
    hist_count<<<256, 256, 0, stream>>>(dst, src, part_din, part_dout, rankpack16);
    deg_reduce<<<NN / 512, 256, 0, stream>>>(part_din, part_dout, repbase_w, ro, ri, din);

    // 2) CSR by dst: scan + atomic-free fill
    scanA<<<NN / 1024, 256, 0, stream>>>(din, blks);
    scanB<<<1, 256, 0, stream>>>(blks, offs + NN);
    scanC<<<NN / 1024, 256, 0, stream>>>(din, blks, offs);
    fill_csr<<<EE / 256, 256, 0, stream>>>(src, dst, ew, ro, offs,
                                           (const unsigned short*)repbase_w, rankpack16, edg);

    // 3) conv layer 1: gather x (64 dims), then GEMM + fused GraphNorm1
    cvt_x<<<NN * 64 / 1024, 256, 0, stream>>>(x, xbf);
    transp_cvt<<<dim3(128 / 32, 64 / 32), 256, 0, stream>>>(W1, w1t, 64, 128);
    gather64<<<NN / 4, 256, 0, stream>>>(xbf, offs, edg, aggx);
    conv1_gn<<<NN / 128, 256, 0, stream>>>(aggx, w1t, ri, a1, g1, b1, Bbf);   // Bbf = gn1

    // 4) conv layer 2: GEMM, then fused gather + GraphNorm2
    transp_cvt<<<dim3(96 / 32, 128 / 32), 256, 0, stream>>>(W2, w2t, 128, 96);
    conv2_mfma<<<NN / 128, 256, 0, stream>>>(Bbf, w2t, Abf);                  // h2 (xbf/aggx dead)
    gather_gn2<<<BB, 256, 0, stream>>>(Abf, offs, edg, ri, a2, g2, b2, Bbf);  // Bbf = gn2 (MLP input)

    // 5) MLP
    transp_cvt<<<dim3(HID / 32, INMLP / 32), 256, 0, stream>>>(Win, WinT, INMLP, HID);
    mlp1_mfma<<<dim3(BB / 128, HID / 128), 256, 0, stream>>>(Bbf, WinT, D);
    transp_cvt<<<dim3(HID4 / 32, HID / 32), 256, 0, stream>>>(Whid, WhidT, HID, HID4);
    transp_cvt<<<dim3(OUTF / 32, HID4 / 32), 256, 0, stream>>>(Wcls, WclsT, HID4, OUTF);
    rownorm<HID><<<BB, 256, 0, stream>>>(D);
    mfma_gemm_af32<true><<<dim3(BB / 64, HID4 / 64), 256, 0, stream>>>(D, WhidT, Y2, BB, HID4, HID);
    rownorm<HID4><<<BB, 256, 0, stream>>>(Y2);
    mfma_gemm_af32<false><<<dim3(BB / 64, OUTF / 64), 256, 0, stream>>>(Y2, WclsT, out, BB, OUTF, HID4);
}

// Round 10
// 842.978 us; speedup vs baseline: 1.1980x; 1.1980x over previous
//
#include <hip/hip_runtime.h>
#include <hip/hip_bf16.h>

// Problem constants (fixed-shape problem)
#define NN 262144      // nodes = 4096 graphs * 64
#define EE 2097152     // edges
#define BB 4096        // graphs
constexpr int INMLP = 6144;
constexpr int HID = 2048;
constexpr int HID4 = 512;
constexpr int OUTF = 256;
constexpr int NSL = 64;            // edge slices
constexpr int ESL = EE / NSL;      // 32768 edges per slice
constexpr int RNODES = 32768;      // nodes per range (8 ranges)

typedef short s16x8 __attribute__((ext_vector_type(8)));   // 8 bf16 in 4 VGPRs
typedef short s16x4 __attribute__((ext_vector_type(4)));
typedef float f32x4 __attribute__((ext_vector_type(4)));

__device__ __forceinline__ float lrelu(float v) { return v >= 0.f ? v : 0.01f * v; }
__device__ __forceinline__ float bf2f(short s) {
    unsigned int u = ((unsigned int)(unsigned short)s) << 16;
    return __builtin_bit_cast(float, u);
}
__device__ __forceinline__ short f2bf(float f) {   // RNE
    unsigned int u = __builtin_bit_cast(unsigned int, f);
    u = (u + 0x7fff + ((u >> 16) & 1)) >> 16;
    return (short)u;
}
// async global->LDS, 16B per lane. LDS dest = wave-uniform base + lane*16.
__device__ __forceinline__ void async16(const void* g, void* l) {
    __builtin_amdgcn_global_load_lds((__attribute__((address_space(1))) void*)g,
                                     (__attribute__((address_space(3))) void*)l, 16, 0, 0);
}

// ---------------- degree counting via LDS histograms (no global atomics) ----------------
// Grid 1024 = type(2) x range(8) x slice(64). Each block: 64KB LDS histogram of packed-u16
// counters for its 32768-node range; streams its 32768-edge slice with int4 loads (4-way ILP);
// LDS atomicAdd (CU-local). dst blocks also capture edge rank within (node, slice) -> rankpack16.
__global__ __launch_bounds__(256) void hist_count(const int* __restrict__ dst, const int* __restrict__ src,
                                                  unsigned* __restrict__ part_din, unsigned* __restrict__ part_dout,
                                                  unsigned short* __restrict__ rankpack16) {
    __shared__ unsigned hist[RNODES / 2];   // 65536 B
    const int S = blockIdx.x & 63;
    const int R = (blockIdx.x >> 6) & 7;
    const int T = blockIdx.x >> 9;          // 0 = din(dst)+rank, 1 = dout(src)
    for (int i = threadIdx.x; i < RNODES / 2; i += 256) hist[i] = 0;
    __syncthreads();
    const int* idxarr = T ? src : dst;
    const int4* v4 = (const int4*)(idxarr + S * ESL);
#pragma unroll 4
    for (int i = 0; i < ESL / 4 / 256; i++) {            // 32 iterations
        const int q0 = i * 256 + threadIdx.x;
        int4 q = v4[q0];
        const int ebase = S * ESL + q0 * 4;
#pragma unroll
        for (int k = 0; k < 4; k++) {
            int idx = k == 0 ? q.x : k == 1 ? q.y : k == 2 ? q.z : q.w;
            if ((idx >> 15) == R) {
                int local = idx & (RNODES - 1);
                unsigned old = atomicAdd(&hist[local >> 1], 1u << ((local & 1) * 16));
                if (T == 0) {
                    unsigned rank = (old >> ((local & 1) * 16)) & 0xffffu;
                    rankpack16[ebase + k] = (unsigned short)((S << 10) | rank);   // rank < 1024
                }
            }
        }
    }
    __syncthreads();
    unsigned* dp = (T ? part_dout : part_din) + (size_t)S * (NN / 2) + R * (RNODES / 2);
    for (int i = threadIdx.x; i < RNODES / 2; i += 256) dp[i] = hist[i];
}

// ---------------- reduce slices: degrees, rsqrt factors, per-(slice,node) base offsets ----------------
// One thread per packed word (2 nodes). repbase stored as packed u16 pairs, same layout.
__global__ __launch_bounds__(256) void deg_reduce(const unsigned* __restrict__ part_din,
                                                  const unsigned* __restrict__ part_dout,
                                                  unsigned* __restrict__ repbase_w,   // [NSL][NN/2] packed u16
                                                  float* __restrict__ ro, float* __restrict__ ri,
                                                  int* __restrict__ din) {
    int i = blockIdx.x * 256 + threadIdx.x;    // word index over NN/2
    unsigned runl = 0, runh = 0, dl = 0, dh = 0;
#pragma unroll 8
    for (int S = 0; S < NSL; S++) {
        repbase_w[(size_t)S * (NN / 2) + i] = (runl & 0xffffu) | (runh << 16);
        unsigned w = part_din[(size_t)S * (NN / 2) + i];
        runl += w & 0xffffu; runh += w >> 16;
        unsigned w2 = part_dout[(size_t)S * (NN / 2) + i];
        dl += w2 & 0xffffu; dh += w2 >> 16;
    }
    int n0 = 2 * i, n1 = 2 * i + 1;
    din[n0] = (int)runl; din[n1] = (int)runh;
    ro[n0] = rsqrtf((float)(dl < 1u ? 1u : dl));
    ro[n1] = rsqrtf((float)(dh < 1u ? 1u : dh));
    ri[n0] = rsqrtf((float)(runl < 1u ? 1u : runl));
    ri[n1] = rsqrtf((float)(runh < 1u ? 1u : runh));
}

// ---------------- scan (exclusive prefix over din counts -> CSR offsets) ----------------
__global__ __launch_bounds__(256) void scanA(const int* __restrict__ cnt, int* __restrict__ blks) {
    __shared__ int s[256];
    int t = threadIdx.x;
    int i0 = blockIdx.x * 1024 + t * 4;
    int ts = cnt[i0] + cnt[i0 + 1] + cnt[i0 + 2] + cnt[i0 + 3];
    s[t] = ts; __syncthreads();
    for (int d = 128; d > 0; d >>= 1) { if (t < d) s[t] += s[t + d]; __syncthreads(); }
    if (t == 0) blks[blockIdx.x] = s[0];
}

__global__ __launch_bounds__(256) void scanB(int* __restrict__ blks, int* __restrict__ offN) {
    __shared__ int s[256];
    int t = threadIdx.x;
    int v = blks[t]; s[t] = v; __syncthreads();
    for (int d = 1; d < 256; d <<= 1) {
        int x = (t >= d) ? s[t - d] : 0; __syncthreads();
        s[t] += x; __syncthreads();
    }
    blks[t] = s[t] - v;            // exclusive
    if (t == 255) *offN = s[255];  // total = EE
}

__global__ __launch_bounds__(256) void scanC(const int* __restrict__ cnt, const int* __restrict__ blkoff,
                                             int* __restrict__ off) {
    __shared__ int s[256];
    int t = threadIdx.x;
    int i0 = blockIdx.x * 1024 + t * 4;
    int v0 = cnt[i0], v1 = cnt[i0 + 1], v2 = cnt[i0 + 2], v3 = cnt[i0 + 3];
    int ts = v0 + v1 + v2 + v3;
    s[t] = ts; __syncthreads();
    for (int d = 1; d < 256; d <<= 1) {
        int x = (t >= d) ? s[t - d] : 0; __syncthreads();
        s[t] += x; __syncthreads();
    }
    int base = blkoff[blockIdx.x] + (s[t] - ts);
    off[i0] = base; off[i0 + 1] = base + v0; off[i0 + 2] = base + v0 + v1; off[i0 + 3] = base + v0 + v1 + v2;
}

// ---------------- fill CSR: atomic-free scatter via (slice, rank) + repbase ----------------
// edge record = int2 { src, bf32(ew * ro[src]) }  (ro folded in by linearity)
__global__ __launch_bounds__(256) void fill_csr(const int* __restrict__ src, const int* __restrict__ dst,
                                                const float* __restrict__ ew, const float* __restrict__ ro,
                                                const int* __restrict__ off,
                                                const unsigned short* __restrict__ repbase16,  // [NSL][NN]
                                                const unsigned short* __restrict__ rankpack16,
                                                int2* __restrict__ edg) {
    int e = blockIdx.x * 256 + threadIdx.x;
    int d = dst[e];
    int s = src[e];
    unsigned pk = rankpack16[e];
    int S = pk >> 10, rank = pk & 1023;
    int p = off[d] + (int)repbase16[(size_t)S * NN + d] + rank;
    edg[p] = make_int2(s, __builtin_bit_cast(int, ew[e] * ro[s]));
}

// ---------------- x fp32 -> bf16 ----------------
__global__ __launch_bounds__(256) void cvt_x(const float* __restrict__ X, short* __restrict__ Xb) {
    int i = (blockIdx.x * 256 + threadIdx.x) * 4;
    float4 v = *(const float4*)(X + i);
    s16x4 o = { f2bf(v.x), f2bf(v.y), f2bf(v.z), f2bf(v.w) };
    *(s16x4*)(Xb + i) = o;
}

// ---------------- gather 64 dims, edge-parallel: 8 edges x 8 chunks of 8 dims ----------------
__global__ __launch_bounds__(256) void gather64(const short* __restrict__ Xb, const int* __restrict__ offs,
                                                const int2* __restrict__ edg, short* __restrict__ Out) {
    const int lane = threadIdx.x & 63;
    const int e = lane >> 3, c = lane & 7;
    int node = blockIdx.x * 4 + (threadIdx.x >> 6);
    node = __builtin_amdgcn_readfirstlane(node);
    const int s0 = offs[node], s1 = offs[node + 1];
    float acc[8] = {};
    for (int j0 = s0; j0 < s1; j0 += 8) {
        int j = j0 + e;
        bool ok = j < s1;
        int2 pe = edg[ok ? j : s0];
        int s = pe.x;
        float w = ok ? __builtin_bit_cast(float, pe.y) : 0.f;
        s16x8 v = *(const s16x8*)&Xb[(size_t)s * 64 + c * 8];
#pragma unroll
        for (int k = 0; k < 8; k++) acc[k] = fmaf(w, bf2f(v[k]), acc[k]);
    }
#pragma unroll
    for (int off = 8; off <= 32; off <<= 1)
#pragma unroll
        for (int k = 0; k < 8; k++) acc[k] += __shfl_xor(acc[k], off);
    if (e == 0) {
        s16x8 o;
#pragma unroll
        for (int k = 0; k < 8; k++) o[k] = f2bf(acc[k]);
        *(s16x8*)&Out[(size_t)node * 64 + c * 8] = o;
    }
}

// ---------------- conv1 + GraphNorm1 fused: MFMA 262144x128x64, block = 128 rows = 2 graphs ----------------
__global__ __launch_bounds__(256) void conv1_gn(const short* __restrict__ A, const short* __restrict__ BT,
                                                const float* __restrict__ ri,
                                                const float* __restrict__ alpha, const float* __restrict__ gamma,
                                                const float* __restrict__ beta, short* __restrict__ Outp) {
    __shared__ short As[128][72];
    __shared__ short Bs[128][72];
    __shared__ float sscale[2][128], sshift[2][128];
    const int t = threadIdx.x;
    const int bm = blockIdx.x * 128;
    const int wave = t >> 6, lane = t & 63;
    const int wm = (wave & 1) * 64, wn = (wave >> 1) * 64;
    const int g = wave & 1;
    const int m16 = lane & 15, quad = lane >> 4;
#pragma unroll
    for (int i = 0; i < 4; i++) {
        int idx = t + 256 * i;
        int rr = idx >> 3, kk = (idx & 7) * 8;
        *(s16x8*)&As[rr][kk] = *(const s16x8*)&A[(size_t)(bm + rr) * 64 + kk];
        *(s16x8*)&Bs[rr][kk] = *(const s16x8*)&BT[(size_t)rr * 64 + kk];
    }
    __syncthreads();
    f32x4 acc[4][4] = {};
#pragma unroll
    for (int kc = 0; kc < 2; kc++) {
        s16x8 af[4], bfr[4];
#pragma unroll
        for (int mt = 0; mt < 4; mt++) af[mt] = *(const s16x8*)&As[wm + mt * 16 + m16][kc * 32 + quad * 8];
#pragma unroll
        for (int nt = 0; nt < 4; nt++) bfr[nt] = *(const s16x8*)&Bs[wn + nt * 16 + m16][kc * 32 + quad * 8];
#pragma unroll
        for (int mt = 0; mt < 4; mt++)
#pragma unroll
            for (int nt = 0; nt < 4; nt++)
                acc[mt][nt] = __builtin_amdgcn_mfma_f32_16x16x32_bf16(af[mt], bfr[nt], acc[mt][nt], 0, 0, 0);
    }
    // transform in place: v = lrelu(h1 * ri[row])
#pragma unroll
    for (int mt = 0; mt < 4; mt++)
#pragma unroll
        for (int r4 = 0; r4 < 4; r4++) {
            float rv = ri[bm + wm + mt * 16 + quad * 4 + r4];
#pragma unroll
            for (int nt = 0; nt < 4; nt++)
                acc[mt][nt][r4] = lrelu(acc[mt][nt][r4] * rv);
        }
    // per-channel stats: sum over mt,r4 (in-register) + quad (shfl_xor 16,32)
#pragma unroll
    for (int nt = 0; nt < 4; nt++) {
        float s1 = 0.f, s2 = 0.f;
#pragma unroll
        for (int mt = 0; mt < 4; mt++)
#pragma unroll
            for (int r4 = 0; r4 < 4; r4++) { float v = acc[mt][nt][r4]; s1 += v; s2 += v * v; }
        s1 += __shfl_xor(s1, 16); s1 += __shfl_xor(s1, 32);
        s2 += __shfl_xor(s2, 16); s2 += __shfl_xor(s2, 32);
        if (quad == 0) {
            int ch = wn + nt * 16 + m16;
            float m = s1 * (1.f / 64.f);
            float a = alpha[ch];
            float var = s2 * (1.f / 64.f) - m * m * a * (2.f - a);   // E[(v-am)^2]
            float sc = gamma[ch] * rsqrtf(var + 1e-5f);
            sscale[g][ch] = sc;
            sshift[g][ch] = beta[ch] - sc * a * m;
        }
    }
    __syncthreads();
#pragma unroll
    for (int nt = 0; nt < 4; nt++) {
        int ch = wn + nt * 16 + m16;
        float sc = sscale[g][ch], sh = sshift[g][ch];
#pragma unroll
        for (int mt = 0; mt < 4; mt++)
#pragma unroll
            for (int r4 = 0; r4 < 4; r4++) {
                int row = bm + wm + mt * 16 + quad * 4 + r4;
                Outp[(size_t)row * 128 + ch] = f2bf(sc * acc[mt][nt][r4] + sh);
            }
    }
}

// ---------------- conv2: MFMA GEMM 262144x96x128, A=gn1 bf16, BT=W2T bf16 (96x128), out h2 bf16 ----------------
__global__ __launch_bounds__(256) void conv2_mfma(const short* __restrict__ A, const short* __restrict__ BT,
                                                  short* __restrict__ H) {
    __shared__ short As[128][136];   // 128 k + 8 pad
    __shared__ short Bs[96][136];
    const int t = threadIdx.x;
    const int bm = blockIdx.x * 128;
    const int wave = t >> 6, lane = t & 63;
    const int wm = (wave & 1) * 64, wn = (wave >> 1) * 48;
    const int m16 = lane & 15, quad = lane >> 4;
#pragma unroll
    for (int i = 0; i < 8; i++) {
        int idx = t + 256 * i;
        int rr = idx >> 4, kk = (idx & 15) * 8;
        *(s16x8*)&As[rr][kk] = *(const s16x8*)&A[(size_t)(bm + rr) * 128 + kk];
    }
#pragma unroll
    for (int i = 0; i < 6; i++) {
        int idx = t + 256 * i;
        int nr = idx >> 4, kk = (idx & 15) * 8;
        *(s16x8*)&Bs[nr][kk] = *(const s16x8*)&BT[(size_t)nr * 128 + kk];
    }
    __syncthreads();
    f32x4 acc[4][3] = {};
#pragma unroll
    for (int kc = 0; kc < 4; kc++) {
        s16x8 af[4], bfr[3];
#pragma unroll
        for (int mt = 0; mt < 4; mt++) af[mt] = *(const s16x8*)&As[wm + mt * 16 + m16][kc * 32 + quad * 8];
#pragma unroll
        for (int nt = 0; nt < 3; nt++) bfr[nt] = *(const s16x8*)&Bs[wn + nt * 16 + m16][kc * 32 + quad * 8];
#pragma unroll
        for (int mt = 0; mt < 4; mt++)
#pragma unroll
            for (int nt = 0; nt < 3; nt++)
                acc[mt][nt] = __builtin_amdgcn_mfma_f32_16x16x32_bf16(af[mt], bfr[nt], acc[mt][nt], 0, 0, 0);
    }
#pragma unroll
    for (int mt = 0; mt < 4; mt++)
#pragma unroll
        for (int r4 = 0; r4 < 4; r4++) {
            int row = bm + wm + mt * 16 + quad * 4 + r4;
#pragma unroll
            for (int nt = 0; nt < 3; nt++)
                H[(size_t)row * 96 + wn + nt * 16 + m16] = f2bf(acc[mt][nt][r4]);
        }
}

// ---------------- gather 96 dims + GraphNorm2 fused: block = 1 graph (64 nodes) ----------------
__global__ __launch_bounds__(256) void gather_gn2(const short* __restrict__ H, const int* __restrict__ offs,
                                                  const int2* __restrict__ edg,
                                                  const float* __restrict__ ri,
                                                  const float* __restrict__ alpha, const float* __restrict__ gamma,
                                                  const float* __restrict__ beta, short* __restrict__ Outp) {
    __shared__ float sm[64 * 96];
    __shared__ float sscale[96], sshift[96];
    const int g = blockIdx.x;
    const int wave = threadIdx.x >> 6, lane = threadIdx.x & 63;
    const int e = lane >> 4, c = lane & 15;
    for (int nl = wave * 16; nl < wave * 16 + 16; nl++) {
        const int node = g * 64 + nl;
        const int s0 = offs[node], s1 = offs[node + 1];
        float acc[6] = {};
        for (int j0 = s0; j0 < s1; j0 += 4) {
            int j = j0 + e;
            bool ok = j < s1;
            int2 pe = edg[ok ? j : s0];
            int s = pe.x;
            float w = ok ? __builtin_bit_cast(float, pe.y) : 0.f;
            const unsigned int* hp = (const unsigned int*)(H + (size_t)s * 96 + c * 6);
            unsigned int u0 = hp[0], u1 = hp[1], u2 = hp[2];
            acc[0] = fmaf(w, bf2f((short)(u0 & 0xffff)), acc[0]);
            acc[1] = fmaf(w, bf2f((short)(u0 >> 16)), acc[1]);
            acc[2] = fmaf(w, bf2f((short)(u1 & 0xffff)), acc[2]);
            acc[3] = fmaf(w, bf2f((short)(u1 >> 16)), acc[3]);
            acc[4] = fmaf(w, bf2f((short)(u2 & 0xffff)), acc[4]);
            acc[5] = fmaf(w, bf2f((short)(u2 >> 16)), acc[5]);
        }
#pragma unroll
        for (int off = 16; off <= 32; off <<= 1)
#pragma unroll
            for (int k = 0; k < 6; k++) acc[k] += __shfl_xor(acc[k], off);
        if (e == 0) {
            float rv = ri[node];
#pragma unroll
            for (int k = 0; k < 6; k++) sm[nl * 96 + c * 6 + k] = lrelu(acc[k] * rv);
        }
    }
    __syncthreads();
    if (threadIdx.x < 96) {
        int cch = threadIdx.x;
        float s1v = 0.f, s2v = 0.f;
#pragma unroll 4
        for (int i = 0; i < 64; i++) { float v = sm[i * 96 + cch]; s1v += v; s2v += v * v; }
        float m = s1v * (1.f / 64.f);
        float a = alpha[cch];
        float var = s2v * (1.f / 64.f) - m * m * a * (2.f - a);
        float sc = gamma[cch] * rsqrtf(var + 1e-5f);
        sscale[cch] = sc;
        sshift[cch] = beta[cch] - sc * a * m;
    }
    __syncthreads();
#pragma unroll
    for (int i = 0; i < 6; i++) {
        int q = threadIdx.x + 256 * i;       // 0..1535
        int nl = q / 24, cq = (q % 24) * 4;
        s16x4 o;
#pragma unroll
        for (int k = 0; k < 4; k++) o[k] = f2bf(sscale[cq + k] * sm[nl * 96 + cq + k] + sshift[cq + k]);
        *(s16x4*)&Outp[(size_t)(g * 64 + nl) * 96 + cq] = o;
    }
}

// ---------------- W fp32 (R x Cc) -> WT bf16 (Cc x R), tiled transpose+convert ----------------
__global__ __launch_bounds__(256) void transp_cvt(const float* __restrict__ W, short* __restrict__ WT,
                                                  int R, int Cc) {
    __shared__ short tile[32][33];
    const int bc = blockIdx.x * 32;   // col of W
    const int br = blockIdx.y * 32;   // row of W
    const int tx = threadIdx.x & 31, ty = threadIdx.x >> 5;   // 32 x 8
#pragma unroll
    for (int i = 0; i < 32; i += 8)
        tile[ty + i][tx] = f2bf(W[(size_t)(br + ty + i) * Cc + bc + tx]);
    __syncthreads();
#pragma unroll
    for (int i = 0; i < 32; i += 8)
        WT[(size_t)(bc + ty + i) * R + br + tx] = tile[tx][ty + i];
}

// ---------------- MLP1: bf16 MFMA GEMM 4096x2048x6144 (global_load_lds BK=64, XOR-swizzled LDS) ----------------
__global__ __launch_bounds__(256) void mlp1_mfma(const short* __restrict__ A, const short* __restrict__ BT,
                                                 float* __restrict__ C) {
    constexpr int K = INMLP, Nn = HID;
    __shared__ short As[128 * 64];
    __shared__ short Bs[128 * 64];
    const int t = threadIdx.x;
    const int bm = blockIdx.x * 128, bn = blockIdx.y * 128;
    const int wave = t >> 6, lane = t & 63;
    const int wm = (wave & 1) * 64, wn = (wave >> 1) * 64;
    const int m16 = lane & 15, quad = lane >> 4;
    const int lrow = lane >> 3, lcol = lane & 7;
    const int scol = lcol ^ (lrow & 7);        // swizzled fetch chunk
    const int xkey = m16 & 7;                  // read-side unswizzle key
    f32x4 acc[4][4] = {};
    for (int k0 = 0; k0 < K; k0 += 64) {
#pragma unroll
        for (int j = 0; j < 4; j++) {
            const int rbase = 32 * wave + 8 * j;   // wave-uniform
            async16(&A[(size_t)(bm + rbase + lrow) * K + k0 + scol * 8], &As[rbase * 64]);
            async16(&BT[(size_t)(bn + rbase + lrow) * K + k0 + scol * 8], &Bs[rbase * 64]);
        }
        __syncthreads();
#pragma unroll
        for (int kc = 0; kc < 2; kc++) {
            s16x8 af[4], bfr[4];
#pragma unroll
            for (int mt = 0; mt < 4; mt++)
                af[mt] = *(const s16x8*)&As[(wm + mt * 16 + m16) * 64 + (((kc * 4 + quad) ^ xkey)) * 8];
#pragma unroll
            for (int nt = 0; nt < 4; nt++)
                bfr[nt] = *(const s16x8*)&Bs[(wn + nt * 16 + m16) * 64 + (((kc * 4 + quad) ^ xkey)) * 8];
#pragma unroll
            for (int mt = 0; mt < 4; mt++)
#pragma unroll
                for (int nt = 0; nt < 4; nt++)
                    acc[mt][nt] = __builtin_amdgcn_mfma_f32_16x16x32_bf16(af[mt], bfr[nt], acc[mt][nt], 0, 0, 0);
        }
        __syncthreads();
    }
#pragma unroll
    for (int mt = 0; mt < 4; mt++)
#pragma unroll
        for (int nt = 0; nt < 4; nt++)
#pragma unroll
            for (int r4 = 0; r4 < 4; r4++) {
                int row = bm + wm + mt * 16 + quad * 4 + r4;
                int col = bn + wn + nt * 16 + m16;
                C[(size_t)row * Nn + col] = lrelu(acc[mt][nt][r4]);
            }
}

// ---------------- generic MFMA GEMM: A fp32 (converted on stage), BT bf16, C fp32 ----------------
template <bool LEAKY>
__global__ __launch_bounds__(256) void mfma_gemm_af32(const float* __restrict__ A, const short* __restrict__ BT,
                                                      float* __restrict__ C, int M, int Nn, int K) {
    __shared__ short As[64][40];
    __shared__ short Bs[64][40];
    const int t = threadIdx.x;
    const int bm = blockIdx.x * 64, bn = blockIdx.y * 64;
    const int wave = t >> 6, lane = t & 63;
    const int wm = (wave & 1) * 32, wn = (wave >> 1) * 32;
    const int m16 = lane & 15, quad = lane >> 4;
    const int rr = t >> 2, kk = (t & 3) * 8;
    f32x4 acc[2][2] = {};
    for (int k0 = 0; k0 < K; k0 += 32) {
        const float* ap = &A[(size_t)(bm + rr) * K + k0 + kk];
        float4 v0 = *(const float4*)ap;
        float4 v1 = *(const float4*)(ap + 4);
        s16x8 a8;
        a8[0] = f2bf(v0.x); a8[1] = f2bf(v0.y); a8[2] = f2bf(v0.z); a8[3] = f2bf(v0.w);
        a8[4] = f2bf(v1.x); a8[5] = f2bf(v1.y); a8[6] = f2bf(v1.z); a8[7] = f2bf(v1.w);
        *(s16x8*)&As[rr][kk] = a8;
        *(s16x8*)&Bs[rr][kk] = *(const s16x8*)&BT[(size_t)(bn + rr) * K + k0 + kk];
        __syncthreads();
        s16x8 af[2], bfr[2];
#pragma unroll
        for (int mt = 0; mt < 2; mt++) af[mt] = *(const s16x8*)&As[wm + mt * 16 + m16][quad * 8];
#pragma unroll
        for (int nt = 0; nt < 2; nt++) bfr[nt] = *(const s16x8*)&Bs[wn + nt * 16 + m16][quad * 8];
#pragma unroll
        for (int mt = 0; mt < 2; mt++)
#pragma unroll
            for (int nt = 0; nt < 2; nt++)
                acc[mt][nt] = __builtin_amdgcn_mfma_f32_16x16x32_bf16(af[mt], bfr[nt], acc[mt][nt], 0, 0, 0);
        __syncthreads();
    }
#pragma unroll
    for (int mt = 0; mt < 2; mt++)
#pragma unroll
        for (int nt = 0; nt < 2; nt++)
#pragma unroll
            for (int r4 = 0; r4 < 4; r4++) {
                int row = bm + wm + mt * 16 + quad * 4 + r4;
                int col = bn + wn + nt * 16 + m16;
                float v = acc[mt][nt][r4];
                if (LEAKY) v = lrelu(v);
                C[(size_t)row * Nn + col] = v;
            }
}

// ---------------- per-row InstanceNorm (in place, fp32) ----------------
template <int NC>
__global__ __launch_bounds__(256) void rownorm(float* __restrict__ Y) {
    float* p = Y + (size_t)blockIdx.x * NC;
    float s1 = 0.f, s2 = 0.f;
    for (int c = threadIdx.x; c < NC; c += 256) { float v = p[c]; s1 += v; s2 += v * v; }
#pragma unroll
    for (int o = 32; o > 0; o >>= 1) { s1 += __shfl_down(s1, o); s2 += __shfl_down(s2, o); }
    __shared__ float w1[4], w2[4];
    if ((threadIdx.x & 63) == 0) { w1[threadIdx.x >> 6] = s1; w2[threadIdx.x >> 6] = s2; }
    __syncthreads();
    s1 = w1[0] + w1[1] + w1[2] + w1[3];
    s2 = w2[0] + w2[1] + w2[2] + w2[3];
    float m = s1 * (1.f / NC);
    float inv = rsqrtf(s2 * (1.f / NC) - m * m + 1e-5f);
    for (int c = threadIdx.x; c < NC; c += 256) p[c] = (p[c] - m) * inv;
}

extern "C" void kernel_launch(void* const* d_in, const int* in_sizes, int n_in,
                              void* d_out, int out_size, void* d_ws, size_t ws_size,
                              hipStream_t stream) {
    const float* x    = (const float*)d_in[0];
    const float* ew   = (const float*)d_in[1];
    const int*   src  = (const int*)d_in[2];
    const int*   dst  = (const int*)d_in[3];
    const float* W1   = (const float*)d_in[4];
    const float* W2   = (const float*)d_in[5];
    const float* a1   = (const float*)d_in[6];
    const float* g1   = (const float*)d_in[7];
    const float* b1   = (const float*)d_in[8];
    const float* a2   = (const float*)d_in[9];
    const float* g2   = (const float*)d_in[10];
    const float* b2   = (const float*)d_in[11];
    const float* Win  = (const float*)d_in[12];
    const float* Whid = (const float*)d_in[13];
    const float* Wcls = (const float*)d_in[14];
    float* out = (float*)d_out;

    // ---- workspace layout (~141 MB fixed) ----
    float* ro   = (float*)d_ws;                    // NN
    float* ri   = ro + NN;                         // NN
    int*   din  = (int*)(ri + NN);                 // NN (deg_in for scan)
    int*   offs = din + NN;                        // NN+4
    int*   blks = offs + NN + 4;                   // 256
    short* w1t  = (short*)(blks + 256);            // 128*64 bf16
    short* w2t  = w1t + 128 * 64;                  // 96*128 bf16
    int2*  edg  = (int2*)(((size_t)(w2t + 96 * 128) + 15) & ~(size_t)15);   // EE int2 (src, ew*ro)
    short* Abf  = (short*)(edg + EE);              // NN*128 bf16 region (64 MiB)
    short* Bbf  = Abf + (size_t)NN * 128;          // NN*128 bf16 region (64 MiB)
    short* xbf  = Abf;                             // NN*64
    short* aggx = Abf + (size_t)NN * 64;           // NN*64
    // graph-build temps: part arrays exactly fill Abf (64 MiB); repbase+rank in Bbf (37.5 MB)
    unsigned*       part_din   = (unsigned*)Abf;                       // NSL * NN/2 words (32 MiB)
    unsigned*       part_dout  = part_din + (size_t)NSL * (NN / 2);    // 32 MiB
    unsigned*       repbase_w  = (unsigned*)Bbf;                       // NSL * NN/2 words (32 MiB)
    unsigned short* rankpack16 = (unsigned short*)(repbase_w + (size_t)NSL * (NN / 2));  // EE u16 (4 MiB)
    // overlays into Abf region after gather_gn2 (h2 dead):
    short* WinT = Abf;                                                  // 2048*6144 bf16 = 25165824 B
    float* D    = (float*)((char*)Abf + 25165824);                      // 4096*2048 fp32 = 33554432 B
    float* Y2   = (float*)((char*)Abf + 25165824 + 33554432);           // 4096*512 fp32  =  8388608 B
    // overlays into Bbf region after mlp1_mfma consumes it:
    short* WhidT = Bbf;                            // 512*2048 bf16
    short* WclsT = WhidT + (size_t)HID4 * HID;     // 256*512 bf16

    // 1) degrees + per-edge ranks via LDS histograms (1024 blocks, int4 streaming)
    hist_count<<<2 * 8 * NSL, 256, 0, stream>>>(dst, src, part_din, part_dout, rankpack16);
    deg_reduce<<<NN / 512, 256, 0, stream>>>(part_din, part_dout, repbase_w, ro, ri, din);

    // 2) CSR by dst: scan + atomic-free fill
    scanA<<<NN / 1024, 256, 0, stream>>>(din, blks);
    scanB<<<1, 256, 0, stream>>>(blks, offs + NN);
    scanC<<<NN / 1024, 256, 0, stream>>>(din, blks, offs);
    fill_csr<<<EE / 256, 256, 0, stream>>>(src, dst, ew, ro, offs,
                                           (const unsigned short*)repbase_w, rankpack16, edg);

    // 3) conv layer 1: gather x (64 dims), then GEMM + fused GraphNorm1
    cvt_x<<<NN * 64 / 1024, 256, 0, stream>>>(x, xbf);
    transp_cvt<<<dim3(128 / 32, 64 / 32), 256, 0, stream>>>(W1, w1t, 64, 128);
    gather64<<<NN / 4, 256, 0, stream>>>(xbf, offs, edg, aggx);
    conv1_gn<<<NN / 128, 256, 0, stream>>>(aggx, w1t, ri, a1, g1, b1, Bbf);   // Bbf = gn1

    // 4) conv layer 2: GEMM, then fused gather + GraphNorm2
    transp_cvt<<<dim3(96 / 32, 128 / 32), 256, 0, stream>>>(W2, w2t, 128, 96);
    conv2_mfma<<<NN / 128, 256, 0, stream>>>(Bbf, w2t, Abf);                  // h2 (xbf/aggx dead)
    gather_gn2<<<BB, 256, 0, stream>>>(Abf, offs, edg, ri, a2, g2, b2, Bbf);  // Bbf = gn2 (MLP input)

    // 5) MLP
    transp_cvt<<<dim3(HID / 32, INMLP / 32), 256, 0, stream>>>(Win, WinT, INMLP, HID);
    mlp1_mfma<<<dim3(BB / 128, HID / 128), 256, 0, stream>>>(Bbf, WinT, D);
    transp_cvt<<<dim3(HID4 / 32, HID / 32), 256, 0, stream>>>(Whid, WhidT, HID, HID4);
    transp_cvt<<<dim3(OUTF / 32, HID4 / 32), 256, 0, stream>>>(Wcls, WclsT, HID4, OUTF);
    rownorm<HID><<<BB, 256, 0, stream>>>(D);
    mfma_gemm_af32<true><<<dim3(BB / 64, HID4 / 64), 256, 0, stream>>>(D, WhidT, Y2, BB, HID4, HID);
    rownorm<HID4><<<BB, 256, 0, stream>>>(Y2);
    mfma_gemm_af32<false><<<dim3(BB / 64, OUTF / 64), 256, 0, stream>>>(Y2, WclsT, out, BB, OUTF, HID4);
}

// Round 11
// 833.138 us; speedup vs baseline: 1.2122x; 1.0118x over previous
//
#include <hip/hip_runtime.h>
#include <hip/hip_bf16.h>

// Problem constants (fixed-shape problem)
#define NN 262144      // nodes = 4096 graphs * 64
#define EE 2097152     // edges
#define BB 4096        // graphs
constexpr int INMLP = 6144;
constexpr int HID = 2048;
constexpr int HID4 = 512;
constexpr int OUTF = 256;
constexpr int NSL = 64;            // edge slices
constexpr int ESL = EE / NSL;      // 32768 edges per slice
constexpr int RNODES = 32768;      // nodes per range (8 ranges)

typedef short s16x8 __attribute__((ext_vector_type(8)));   // 8 bf16 in 4 VGPRs
typedef short s16x4 __attribute__((ext_vector_type(4)));
typedef float f32x4 __attribute__((ext_vector_type(4)));

__device__ __forceinline__ float lrelu(float v) { return v >= 0.f ? v : 0.01f * v; }
__device__ __forceinline__ float bf2f(short s) {
    unsigned int u = ((unsigned int)(unsigned short)s) << 16;
    return __builtin_bit_cast(float, u);
}
__device__ __forceinline__ short f2bf(float f) {   // RNE
    unsigned int u = __builtin_bit_cast(unsigned int, f);
    u = (u + 0x7fff + ((u >> 16) & 1)) >> 16;
    return (short)u;
}
// async global->LDS, 16B per lane. LDS dest = wave-uniform base + lane*16.
__device__ __forceinline__ void async16(const void* g, void* l) {
    __builtin_amdgcn_global_load_lds((__attribute__((address_space(1))) void*)g,
                                     (__attribute__((address_space(3))) void*)l, 16, 0, 0);
}

// ---------------- degree counting via LDS histograms (no global atomics) ----------------
__global__ __launch_bounds__(256) void hist_count(const int* __restrict__ dst, const int* __restrict__ src,
                                                  unsigned* __restrict__ part_din, unsigned* __restrict__ part_dout,
                                                  unsigned short* __restrict__ rankpack16) {
    __shared__ unsigned hist[RNODES / 2];   // 65536 B
    const int S = blockIdx.x & 63;
    const int R = (blockIdx.x >> 6) & 7;
    const int T = blockIdx.x >> 9;          // 0 = din(dst)+rank, 1 = dout(src)
    for (int i = threadIdx.x; i < RNODES / 2; i += 256) hist[i] = 0;
    __syncthreads();
    const int* idxarr = T ? src : dst;
    const int4* v4 = (const int4*)(idxarr + S * ESL);
#pragma unroll 4
    for (int i = 0; i < ESL / 4 / 256; i++) {            // 32 iterations
        const int q0 = i * 256 + threadIdx.x;
        int4 q = v4[q0];
        const int ebase = S * ESL + q0 * 4;
#pragma unroll
        for (int k = 0; k < 4; k++) {
            int idx = k == 0 ? q.x : k == 1 ? q.y : k == 2 ? q.z : q.w;
            if ((idx >> 15) == R) {
                int local = idx & (RNODES - 1);
                unsigned old = atomicAdd(&hist[local >> 1], 1u << ((local & 1) * 16));
                if (T == 0) {
                    unsigned rank = (old >> ((local & 1) * 16)) & 0xffffu;
                    rankpack16[ebase + k] = (unsigned short)((S << 10) | rank);   // rank < 1024
                }
            }
        }
    }
    __syncthreads();
    unsigned* dp = (T ? part_dout : part_din) + (size_t)S * (NN / 2) + R * (RNODES / 2);
    for (int i = threadIdx.x; i < RNODES / 2; i += 256) dp[i] = hist[i];
}

// ---------------- reduce slices: degrees, rsqrt factors, per-(slice,node) base offsets ----------------
__global__ __launch_bounds__(256) void deg_reduce(const unsigned* __restrict__ part_din,
                                                  const unsigned* __restrict__ part_dout,
                                                  unsigned* __restrict__ repbase_w,   // [NSL][NN/2] packed u16
                                                  float* __restrict__ ro, float* __restrict__ ri,
                                                  int* __restrict__ din) {
    int i = blockIdx.x * 256 + threadIdx.x;    // word index over NN/2
    unsigned runl = 0, runh = 0, dl = 0, dh = 0;
#pragma unroll 8
    for (int S = 0; S < NSL; S++) {
        repbase_w[(size_t)S * (NN / 2) + i] = (runl & 0xffffu) | (runh << 16);
        unsigned w = part_din[(size_t)S * (NN / 2) + i];
        runl += w & 0xffffu; runh += w >> 16;
        unsigned w2 = part_dout[(size_t)S * (NN / 2) + i];
        dl += w2 & 0xffffu; dh += w2 >> 16;
    }
    int n0 = 2 * i, n1 = 2 * i + 1;
    din[n0] = (int)runl; din[n1] = (int)runh;
    ro[n0] = rsqrtf((float)(dl < 1u ? 1u : dl));
    ro[n1] = rsqrtf((float)(dh < 1u ? 1u : dh));
    ri[n0] = rsqrtf((float)(runl < 1u ? 1u : runl));
    ri[n1] = rsqrtf((float)(runh < 1u ? 1u : runh));
}

// ---------------- scan (exclusive prefix over din counts -> CSR offsets) ----------------
__global__ __launch_bounds__(256) void scanA(const int* __restrict__ cnt, int* __restrict__ blks) {
    __shared__ int s[256];
    int t = threadIdx.x;
    int i0 = blockIdx.x * 1024 + t * 4;
    int ts = cnt[i0] + cnt[i0 + 1] + cnt[i0 + 2] + cnt[i0 + 3];
    s[t] = ts; __syncthreads();
    for (int d = 128; d > 0; d >>= 1) { if (t < d) s[t] += s[t + d]; __syncthreads(); }
    if (t == 0) blks[blockIdx.x] = s[0];
}

__global__ __launch_bounds__(256) void scanB(int* __restrict__ blks, int* __restrict__ offN) {
    __shared__ int s[256];
    int t = threadIdx.x;
    int v = blks[t]; s[t] = v; __syncthreads();
    for (int d = 1; d < 256; d <<= 1) {
        int x = (t >= d) ? s[t - d] : 0; __syncthreads();
        s[t] += x; __syncthreads();
    }
    blks[t] = s[t] - v;            // exclusive
    if (t == 255) *offN = s[255];  // total = EE
}

__global__ __launch_bounds__(256) void scanC(const int* __restrict__ cnt, const int* __restrict__ blkoff,
                                             int* __restrict__ off) {
    __shared__ int s[256];
    int t = threadIdx.x;
    int i0 = blockIdx.x * 1024 + t * 4;
    int v0 = cnt[i0], v1 = cnt[i0 + 1], v2 = cnt[i0 + 2], v3 = cnt[i0 + 3];
    int ts = v0 + v1 + v2 + v3;
    s[t] = ts; __syncthreads();
    for (int d = 1; d < 256; d <<= 1) {
        int x = (t >= d) ? s[t - d] : 0; __syncthreads();
        s[t] += x; __syncthreads();
    }
    int base = blkoff[blockIdx.x] + (s[t] - ts);
    off[i0] = base; off[i0 + 1] = base + v0; off[i0 + 2] = base + v0 + v1; off[i0 + 3] = base + v0 + v1 + v2;
}

// ---------------- fill CSR: atomic-free scatter via (slice, rank) + repbase ----------------
__global__ __launch_bounds__(256) void fill_csr(const int* __restrict__ src, const int* __restrict__ dst,
                                                const float* __restrict__ ew, const float* __restrict__ ro,
                                                const int* __restrict__ off,
                                                const unsigned short* __restrict__ repbase16,  // [NSL][NN]
                                                const unsigned short* __restrict__ rankpack16,
                                                int2* __restrict__ edg) {
    int e = blockIdx.x * 256 + threadIdx.x;
    int d = dst[e];
    int s = src[e];
    unsigned pk = rankpack16[e];
    int S = pk >> 10, rank = pk & 1023;
    int p = off[d] + (int)repbase16[(size_t)S * NN + d] + rank;
    edg[p] = make_int2(s, __builtin_bit_cast(int, ew[e] * ro[s]));
}

// ---------------- x fp32 -> bf16 ----------------
__global__ __launch_bounds__(256) void cvt_x(const float* __restrict__ X, short* __restrict__ Xb) {
    int i = (blockIdx.x * 256 + threadIdx.x) * 4;
    float4 v = *(const float4*)(X + i);
    s16x4 o = { f2bf(v.x), f2bf(v.y), f2bf(v.z), f2bf(v.w) };
    *(s16x4*)(Xb + i) = o;
}

// ---------------- gather 64 dims, wave-per-node, edge-parallel 8 edges x 8 chunks of 8 dims ----------------
__global__ __launch_bounds__(256) void gather64(const short* __restrict__ Xb, const int* __restrict__ offs,
                                                const int2* __restrict__ edg, short* __restrict__ Out) {
    const int lane = threadIdx.x & 63;
    const int e = lane >> 3, c = lane & 7;
    int node = blockIdx.x * 4 + (threadIdx.x >> 6);
    node = __builtin_amdgcn_readfirstlane(node);
    const int s0 = offs[node], s1 = offs[node + 1];
    float acc[8] = {};
    for (int j0 = s0; j0 < s1; j0 += 8) {
        int j = j0 + e;
        bool ok = j < s1;
        int2 pe = edg[ok ? j : s0];
        int s = pe.x;
        float w = ok ? __builtin_bit_cast(float, pe.y) : 0.f;
        s16x8 v = *(const s16x8*)&Xb[(size_t)s * 64 + c * 8];
#pragma unroll
        for (int k = 0; k < 8; k++) acc[k] = fmaf(w, bf2f(v[k]), acc[k]);
    }
#pragma unroll
    for (int off = 8; off <= 32; off <<= 1)
#pragma unroll
        for (int k = 0; k < 8; k++) acc[k] += __shfl_xor(acc[k], off);
    if (e == 0) {
        s16x8 o;
#pragma unroll
        for (int k = 0; k < 8; k++) o[k] = f2bf(acc[k]);
        *(s16x8*)&Out[(size_t)node * 64 + c * 8] = o;
    }
}

// ---------------- gather 96 dims, wave-per-node, edge-parallel 4 edges x 16 chunks of 6 dims ----------------
__global__ __launch_bounds__(256) void gather96(const short* __restrict__ H, const int* __restrict__ offs,
                                                const int2* __restrict__ edg, short* __restrict__ Out) {
    const int lane = threadIdx.x & 63;
    const int e = lane >> 4, c = lane & 15;
    int node = blockIdx.x * 4 + (threadIdx.x >> 6);
    node = __builtin_amdgcn_readfirstlane(node);
    const int s0 = offs[node], s1 = offs[node + 1];
    float acc[6] = {};
    for (int j0 = s0; j0 < s1; j0 += 4) {
        int j = j0 + e;
        bool ok = j < s1;
        int2 pe = edg[ok ? j : s0];
        int s = pe.x;
        float w = ok ? __builtin_bit_cast(float, pe.y) : 0.f;
        const unsigned int* hp = (const unsigned int*)(H + (size_t)s * 96 + c * 6);
        unsigned int u0 = hp[0], u1 = hp[1], u2 = hp[2];
        acc[0] = fmaf(w, bf2f((short)(u0 & 0xffff)), acc[0]);
        acc[1] = fmaf(w, bf2f((short)(u0 >> 16)), acc[1]);
        acc[2] = fmaf(w, bf2f((short)(u1 & 0xffff)), acc[2]);
        acc[3] = fmaf(w, bf2f((short)(u1 >> 16)), acc[3]);
        acc[4] = fmaf(w, bf2f((short)(u2 & 0xffff)), acc[4]);
        acc[5] = fmaf(w, bf2f((short)(u2 >> 16)), acc[5]);
    }
#pragma unroll
    for (int off = 16; off <= 32; off <<= 1)
#pragma unroll
        for (int k = 0; k < 6; k++) acc[k] += __shfl_xor(acc[k], off);
    if (e == 0) {
        unsigned int* op = (unsigned int*)(Out + (size_t)node * 96 + c * 6);
        op[0] = (unsigned short)f2bf(acc[0]) | ((unsigned)(unsigned short)f2bf(acc[1]) << 16);
        op[1] = (unsigned short)f2bf(acc[2]) | ((unsigned)(unsigned short)f2bf(acc[3]) << 16);
        op[2] = (unsigned short)f2bf(acc[4]) | ((unsigned)(unsigned short)f2bf(acc[5]) << 16);
    }
}

// ---------------- fused rsqrt(deg_in)*leaky_relu + GraphNorm (per 64-node graph), bf16 in place ----------------
template <int C>
__global__ __launch_bounds__(256) void graphnorm_k(short* __restrict__ Ag, const float* __restrict__ ri,
                                                   const float* __restrict__ alpha, const float* __restrict__ gamma,
                                                   const float* __restrict__ beta) {
    __shared__ float sm[64 * C];
    __shared__ float sscale[C], sshift[C];
    const int g = blockIdx.x;
    const size_t base = (size_t)g * 64 * C;
    for (int idx = threadIdx.x; idx < 64 * C; idx += 256) {
        int i = idx / C;
        float v = bf2f(Ag[base + idx]) * ri[g * 64 + i];
        sm[idx] = lrelu(v);
    }
    __syncthreads();
    if (threadIdx.x < C) {
        int c = threadIdx.x;
        float s1 = 0.f, s2 = 0.f;
#pragma unroll 4
        for (int i = 0; i < 64; i++) { float v = sm[i * C + c]; s1 += v; s2 += v * v; }
        float m = s1 * (1.f / 64.f);
        float a = alpha[c];
        float var = s2 * (1.f / 64.f) - m * m * a * (2.f - a);   // E[(v-am)^2]
        float sc = gamma[c] * rsqrtf(var + 1e-5f);
        sscale[c] = sc;
        sshift[c] = beta[c] - sc * a * m;
    }
    __syncthreads();
    for (int idx = threadIdx.x; idx < 64 * C; idx += 256) {
        int c = idx % C;
        Ag[base + idx] = f2bf(sscale[c] * sm[idx] + sshift[c]);
    }
}

// ---------------- conv1 + GraphNorm1 fused: MFMA 262144x128x64, block = 128 rows = 2 graphs ----------------
__global__ __launch_bounds__(256) void conv1_gn(const short* __restrict__ A, const short* __restrict__ BT,
                                                const float* __restrict__ ri,
                                                const float* __restrict__ alpha, const float* __restrict__ gamma,
                                                const float* __restrict__ beta, short* __restrict__ Outp) {
    __shared__ short As[128][72];
    __shared__ short Bs[128][72];
    __shared__ float sscale[2][128], sshift[2][128];
    const int t = threadIdx.x;
    const int bm = blockIdx.x * 128;
    const int wave = t >> 6, lane = t & 63;
    const int wm = (wave & 1) * 64, wn = (wave >> 1) * 64;
    const int g = wave & 1;
    const int m16 = lane & 15, quad = lane >> 4;
#pragma unroll
    for (int i = 0; i < 4; i++) {
        int idx = t + 256 * i;
        int rr = idx >> 3, kk = (idx & 7) * 8;
        *(s16x8*)&As[rr][kk] = *(const s16x8*)&A[(size_t)(bm + rr) * 64 + kk];
        *(s16x8*)&Bs[rr][kk] = *(const s16x8*)&BT[(size_t)rr * 64 + kk];
    }
    __syncthreads();
    f32x4 acc[4][4] = {};
#pragma unroll
    for (int kc = 0; kc < 2; kc++) {
        s16x8 af[4], bfr[4];
#pragma unroll
        for (int mt = 0; mt < 4; mt++) af[mt] = *(const s16x8*)&As[wm + mt * 16 + m16][kc * 32 + quad * 8];
#pragma unroll
        for (int nt = 0; nt < 4; nt++) bfr[nt] = *(const s16x8*)&Bs[wn + nt * 16 + m16][kc * 32 + quad * 8];
#pragma unroll
        for (int mt = 0; mt < 4; mt++)
#pragma unroll
            for (int nt = 0; nt < 4; nt++)
                acc[mt][nt] = __builtin_amdgcn_mfma_f32_16x16x32_bf16(af[mt], bfr[nt], acc[mt][nt], 0, 0, 0);
    }
#pragma unroll
    for (int mt = 0; mt < 4; mt++)
#pragma unroll
        for (int r4 = 0; r4 < 4; r4++) {
            float rv = ri[bm + wm + mt * 16 + quad * 4 + r4];
#pragma unroll
            for (int nt = 0; nt < 4; nt++)
                acc[mt][nt][r4] = lrelu(acc[mt][nt][r4] * rv);
        }
#pragma unroll
    for (int nt = 0; nt < 4; nt++) {
        float s1 = 0.f, s2 = 0.f;
#pragma unroll
        for (int mt = 0; mt < 4; mt++)
#pragma unroll
            for (int r4 = 0; r4 < 4; r4++) { float v = acc[mt][nt][r4]; s1 += v; s2 += v * v; }
        s1 += __shfl_xor(s1, 16); s1 += __shfl_xor(s1, 32);
        s2 += __shfl_xor(s2, 16); s2 += __shfl_xor(s2, 32);
        if (quad == 0) {
            int ch = wn + nt * 16 + m16;
            float m = s1 * (1.f / 64.f);
            float a = alpha[ch];
            float var = s2 * (1.f / 64.f) - m * m * a * (2.f - a);   // E[(v-am)^2]
            float sc = gamma[ch] * rsqrtf(var + 1e-5f);
            sscale[g][ch] = sc;
            sshift[g][ch] = beta[ch] - sc * a * m;
        }
    }
    __syncthreads();
#pragma unroll
    for (int nt = 0; nt < 4; nt++) {
        int ch = wn + nt * 16 + m16;
        float sc = sscale[g][ch], sh = sshift[g][ch];
#pragma unroll
        for (int mt = 0; mt < 4; mt++)
#pragma unroll
            for (int r4 = 0; r4 < 4; r4++) {
                int row = bm + wm + mt * 16 + quad * 4 + r4;
                Outp[(size_t)row * 128 + ch] = f2bf(sc * acc[mt][nt][r4] + sh);
            }
    }
}

// ---------------- conv2: MFMA GEMM 262144x96x128, A=gn1 bf16, BT=W2T bf16 (96x128), out h2 bf16 ----------------
__global__ __launch_bounds__(256) void conv2_mfma(const short* __restrict__ A, const short* __restrict__ BT,
                                                  short* __restrict__ H) {
    __shared__ short As[128][136];   // 128 k + 8 pad
    __shared__ short Bs[96][136];
    const int t = threadIdx.x;
    const int bm = blockIdx.x * 128;
    const int wave = t >> 6, lane = t & 63;
    const int wm = (wave & 1) * 64, wn = (wave >> 1) * 48;
    const int m16 = lane & 15, quad = lane >> 4;
#pragma unroll
    for (int i = 0; i < 8; i++) {
        int idx = t + 256 * i;
        int rr = idx >> 4, kk = (idx & 15) * 8;
        *(s16x8*)&As[rr][kk] = *(const s16x8*)&A[(size_t)(bm + rr) * 128 + kk];
    }
#pragma unroll
    for (int i = 0; i < 6; i++) {
        int idx = t + 256 * i;
        int nr = idx >> 4, kk = (idx & 15) * 8;
        *(s16x8*)&Bs[nr][kk] = *(const s16x8*)&BT[(size_t)nr * 128 + kk];
    }
    __syncthreads();
    f32x4 acc[4][3] = {};
#pragma unroll
    for (int kc = 0; kc < 4; kc++) {
        s16x8 af[4], bfr[3];
#pragma unroll
        for (int mt = 0; mt < 4; mt++) af[mt] = *(const s16x8*)&As[wm + mt * 16 + m16][kc * 32 + quad * 8];
#pragma unroll
        for (int nt = 0; nt < 3; nt++) bfr[nt] = *(const s16x8*)&Bs[wn + nt * 16 + m16][kc * 32 + quad * 8];
#pragma unroll
        for (int mt = 0; mt < 4; mt++)
#pragma unroll
            for (int nt = 0; nt < 3; nt++)
                acc[mt][nt] = __builtin_amdgcn_mfma_f32_16x16x32_bf16(af[mt], bfr[nt], acc[mt][nt], 0, 0, 0);
    }
#pragma unroll
    for (int mt = 0; mt < 4; mt++)
#pragma unroll
        for (int r4 = 0; r4 < 4; r4++) {
            int row = bm + wm + mt * 16 + quad * 4 + r4;
#pragma unroll
            for (int nt = 0; nt < 3; nt++)
                H[(size_t)row * 96 + wn + nt * 16 + m16] = f2bf(acc[mt][nt][r4]);
        }
}

// ---------------- W fp32 (R x Cc) -> WT bf16 (Cc x R), tiled transpose+convert ----------------
__global__ __launch_bounds__(256) void transp_cvt(const float* __restrict__ W, short* __restrict__ WT,
                                                  int R, int Cc) {
    __shared__ short tile[32][33];
    const int bc = blockIdx.x * 32;   // col of W
    const int br = blockIdx.y * 32;   // row of W
    const int tx = threadIdx.x & 31, ty = threadIdx.x >> 5;   // 32 x 8
#pragma unroll
    for (int i = 0; i < 32; i += 8)
        tile[ty + i][tx] = f2bf(W[(size_t)(br + ty + i) * Cc + bc + tx]);
    __syncthreads();
#pragma unroll
    for (int i = 0; i < 32; i += 8)
        WT[(size_t)(bc + ty + i) * R + br + tx] = tile[tx][ty + i];
}

// ---------------- MLP1: split-K bf16 MFMA GEMM 4096x2048x6144 (global_load_lds BK=64, XOR-swizzled) ----------------
// blockIdx.z selects K half; partial sums written bf16 (no lrelu) to Cp + z*BB*HID.
__global__ __launch_bounds__(256) void mlp1_mfma(const short* __restrict__ A, const short* __restrict__ BT,
                                                 short* __restrict__ Cp) {
    constexpr int K = INMLP, Nn = HID;
    __shared__ short As[128 * 64];
    __shared__ short Bs[128 * 64];
    const int t = threadIdx.x;
    const int bm = blockIdx.x * 128, bn = blockIdx.y * 128;
    const int kbase = blockIdx.z * (K / 2);
    const int wave = t >> 6, lane = t & 63;
    const int wm = (wave & 1) * 64, wn = (wave >> 1) * 64;
    const int m16 = lane & 15, quad = lane >> 4;
    const int lrow = lane >> 3, lcol = lane & 7;
    const int scol = lcol ^ (lrow & 7);        // swizzled fetch chunk
    const int xkey = m16 & 7;                  // read-side unswizzle key
    f32x4 acc[4][4] = {};
    for (int k0 = kbase; k0 < kbase + K / 2; k0 += 64) {
#pragma unroll
        for (int j = 0; j < 4; j++) {
            const int rbase = 32 * wave + 8 * j;   // wave-uniform
            async16(&A[(size_t)(bm + rbase + lrow) * K + k0 + scol * 8], &As[rbase * 64]);
            async16(&BT[(size_t)(bn + rbase + lrow) * K + k0 + scol * 8], &Bs[rbase * 64]);
        }
        __syncthreads();
#pragma unroll
        for (int kc = 0; kc < 2; kc++) {
            s16x8 af[4], bfr[4];
#pragma unroll
            for (int mt = 0; mt < 4; mt++)
                af[mt] = *(const s16x8*)&As[(wm + mt * 16 + m16) * 64 + (((kc * 4 + quad) ^ xkey)) * 8];
#pragma unroll
            for (int nt = 0; nt < 4; nt++)
                bfr[nt] = *(const s16x8*)&Bs[(wn + nt * 16 + m16) * 64 + (((kc * 4 + quad) ^ xkey)) * 8];
#pragma unroll
            for (int mt = 0; mt < 4; mt++)
#pragma unroll
                for (int nt = 0; nt < 4; nt++)
                    acc[mt][nt] = __builtin_amdgcn_mfma_f32_16x16x32_bf16(af[mt], bfr[nt], acc[mt][nt], 0, 0, 0);
        }
        __syncthreads();
    }
    short* C = Cp + (size_t)blockIdx.z * BB * HID;
#pragma unroll
    for (int mt = 0; mt < 4; mt++)
#pragma unroll
        for (int nt = 0; nt < 4; nt++)
#pragma unroll
            for (int r4 = 0; r4 < 4; r4++) {
                int row = bm + wm + mt * 16 + quad * 4 + r4;
                int col = bn + wn + nt * 16 + m16;
                C[(size_t)row * Nn + col] = f2bf(acc[mt][nt][r4]);
            }
}

// ---------------- combine split-K partials + leaky + InstanceNorm, bf16 in place (D0) ----------------
__global__ __launch_bounds__(256) void rownorm_hid(short* __restrict__ D0, const short* __restrict__ D1) {
    const size_t base = (size_t)blockIdx.x * HID;
    float v[8];
    float s1 = 0.f, s2 = 0.f;
    const int c0 = threadIdx.x * 8;
    {
        s16x8 a = *(const s16x8*)&D0[base + c0];
        s16x8 b = *(const s16x8*)&D1[base + c0];
#pragma unroll
        for (int k = 0; k < 8; k++) {
            float x = lrelu(bf2f(a[k]) + bf2f(b[k]));
            v[k] = x; s1 += x; s2 += x * x;
        }
    }
#pragma unroll
    for (int o = 32; o > 0; o >>= 1) { s1 += __shfl_down(s1, o); s2 += __shfl_down(s2, o); }
    __shared__ float w1[4], w2[4];
    if ((threadIdx.x & 63) == 0) { w1[threadIdx.x >> 6] = s1; w2[threadIdx.x >> 6] = s2; }
    __syncthreads();
    s1 = w1[0] + w1[1] + w1[2] + w1[3];
    s2 = w2[0] + w2[1] + w2[2] + w2[3];
    float m = s1 * (1.f / HID);
    float inv = rsqrtf(s2 * (1.f / HID) - m * m + 1e-5f);
    s16x8 o;
#pragma unroll
    for (int k = 0; k < 8; k++) o[k] = f2bf((v[k] - m) * inv);
    *(s16x8*)&D0[base + c0] = o;
}

// ---------------- generic MFMA GEMM: A bf16 or fp32 (converted on stage), BT bf16, C fp32 ----------------
template <bool ABF16, bool LEAKY>
__global__ __launch_bounds__(256) void mfma_gemm(const float* __restrict__ Af, const short* __restrict__ Ab,
                                                 const short* __restrict__ BT,
                                                 float* __restrict__ C, int M, int Nn, int K) {
    __shared__ short As[64][40];
    __shared__ short Bs[64][40];
    const int t = threadIdx.x;
    const int bm = blockIdx.x * 64, bn = blockIdx.y * 64;
    const int wave = t >> 6, lane = t & 63;
    const int wm = (wave & 1) * 32, wn = (wave >> 1) * 32;
    const int m16 = lane & 15, quad = lane >> 4;
    const int rr = t >> 2, kk = (t & 3) * 8;
    f32x4 acc[2][2] = {};
    for (int k0 = 0; k0 < K; k0 += 32) {
        if (ABF16) {
            *(s16x8*)&As[rr][kk] = *(const s16x8*)&Ab[(size_t)(bm + rr) * K + k0 + kk];
        } else {
            const float* ap = &Af[(size_t)(bm + rr) * K + k0 + kk];
            float4 v0 = *(const float4*)ap;
            float4 v1 = *(const float4*)(ap + 4);
            s16x8 a8;
            a8[0] = f2bf(v0.x); a8[1] = f2bf(v0.y); a8[2] = f2bf(v0.z); a8[3] = f2bf(v0.w);
            a8[4] = f2bf(v1.x); a8[5] = f2bf(v1.y); a8[6] = f2bf(v1.z); a8[7] = f2bf(v1.w);
            *(s16x8*)&As[rr][kk] = a8;
        }
        *(s16x8*)&Bs[rr][kk] = *(const s16x8*)&BT[(size_t)(bn + rr) * K + k0 + kk];
        __syncthreads();
        s16x8 af[2], bfr[2];
#pragma unroll
        for (int mt = 0; mt < 2; mt++) af[mt] = *(const s16x8*)&As[wm + mt * 16 + m16][quad * 8];
#pragma unroll
        for (int nt = 0; nt < 2; nt++) bfr[nt] = *(const s16x8*)&Bs[wn + nt * 16 + m16][quad * 8];
#pragma unroll
        for (int mt = 0; mt < 2; mt++)
#pragma unroll
            for (int nt = 0; nt < 2; nt++)
                acc[mt][nt] = __builtin_amdgcn_mfma_f32_16x16x32_bf16(af[mt], bfr[nt], acc[mt][nt], 0, 0, 0);
        __syncthreads();
    }
#pragma unroll
    for (int mt = 0; mt < 2; mt++)
#pragma unroll
        for (int nt = 0; nt < 2; nt++)
#pragma unroll
            for (int r4 = 0; r4 < 4; r4++) {
                int row = bm + wm + mt * 16 + quad * 4 + r4;
                int col = bn + wn + nt * 16 + m16;
                float v = acc[mt][nt][r4];
                if (LEAKY) v = lrelu(v);
                C[(size_t)row * Nn + col] = v;
            }
}

// ---------------- per-row InstanceNorm (in place, fp32) ----------------
template <int NC>
__global__ __launch_bounds__(256) void rownorm(float* __restrict__ Y) {
    float* p = Y + (size_t)blockIdx.x * NC;
    float s1 = 0.f, s2 = 0.f;
    for (int c = threadIdx.x; c < NC; c += 256) { float v = p[c]; s1 += v; s2 += v * v; }
#pragma unroll
    for (int o = 32; o > 0; o >>= 1) { s1 += __shfl_down(s1, o); s2 += __shfl_down(s2, o); }
    __shared__ float w1[4], w2[4];
    if ((threadIdx.x & 63) == 0) { w1[threadIdx.x >> 6] = s1; w2[threadIdx.x >> 6] = s2; }
    __syncthreads();
    s1 = w1[0] + w1[1] + w1[2] + w1[3];
    s2 = w2[0] + w2[1] + w2[2] + w2[3];
    float m = s1 * (1.f / NC);
    float inv = rsqrtf(s2 * (1.f / NC) - m * m + 1e-5f);
    for (int c = threadIdx.x; c < NC; c += 256) p[c] = (p[c] - m) * inv;
}

extern "C" void kernel_launch(void* const* d_in, const int* in_sizes, int n_in,
                              void* d_out, int out_size, void* d_ws, size_t ws_size,
                              hipStream_t stream) {
    const float* x    = (const float*)d_in[0];
    const float* ew   = (const float*)d_in[1];
    const int*   src  = (const int*)d_in[2];
    const int*   dst  = (const int*)d_in[3];
    const float* W1   = (const float*)d_in[4];
    const float* W2   = (const float*)d_in[5];
    const float* a1   = (const float*)d_in[6];
    const float* g1   = (const float*)d_in[7];
    const float* b1   = (const float*)d_in[8];
    const float* a2   = (const float*)d_in[9];
    const float* g2   = (const float*)d_in[10];
    const float* b2   = (const float*)d_in[11];
    const float* Win  = (const float*)d_in[12];
    const float* Whid = (const float*)d_in[13];
    const float* Wcls = (const float*)d_in[14];
    float* out = (float*)d_out;

    // ---- workspace layout ----
    float* ro   = (float*)d_ws;                    // NN
    float* ri   = ro + NN;                         // NN
    int*   din  = (int*)(ri + NN);                 // NN (deg_in for scan)
    int*   offs = din + NN;                        // NN+4
    int*   blks = offs + NN + 4;                   // 256
    short* w1t  = (short*)(blks + 256);            // 128*64 bf16
    short* w2t  = w1t + 128 * 64;                  // 96*128 bf16
    int2*  edg  = (int2*)(((size_t)(w2t + 96 * 128) + 15) & ~(size_t)15);   // EE int2 (src, ew*ro), 16.8 MB
    short* Abf  = (short*)(edg + EE);              // 64 MiB region
    short* Bbf  = Abf + (size_t)NN * 128;          // 64 MiB region
    short* xbf  = Abf;                             // NN*64
    short* aggx = Abf + (size_t)NN * 64;           // NN*64
    // graph-build temps: part arrays fill Abf; repbase+rank in Bbf
    unsigned*       part_din   = (unsigned*)Abf;                       // NSL * NN/2 words (32 MiB)
    unsigned*       part_dout  = part_din + (size_t)NSL * (NN / 2);    // 32 MiB
    unsigned*       repbase_w  = (unsigned*)Bbf;                       // 32 MiB
    unsigned short* rankpack16 = (unsigned short*)(repbase_w + (size_t)NSL * (NN / 2));  // EE u16
    // overlays into Abf region after gather96 (h2 dead):
    short* WinT = Abf;                                      // 2048*6144 bf16 = 25165824 B
    short* D0   = (short*)((char*)Abf + 25165824);          // 4096*2048 bf16 = 16777216 B
    short* D1   = D0 + (size_t)BB * HID;                    // 4096*2048 bf16 = 16777216 B  (total 58.7 MB <= 64 MiB)
    // Y2 in edg region (edg dead after gather96):
    float* Y2   = (float*)edg;                              // 4096*512 fp32 = 8388608 B <= 16.8 MB
    // overlays into Bbf region after mlp1_mfma consumes gn2:
    short* WhidT = Bbf;                            // 512*2048 bf16
    short* WclsT = WhidT + (size_t)HID4 * HID;     // 256*512 bf16

    // 1) degrees + per-edge ranks via LDS histograms (1024 blocks, int4 streaming)
    hist_count<<<2 * 8 * NSL, 256, 0, stream>>>(dst, src, part_din, part_dout, rankpack16);
    deg_reduce<<<NN / 512, 256, 0, stream>>>(part_din, part_dout, repbase_w, ro, ri, din);

    // 2) CSR by dst: scan + atomic-free fill
    scanA<<<NN / 1024, 256, 0, stream>>>(din, blks);
    scanB<<<1, 256, 0, stream>>>(blks, offs + NN);
    scanC<<<NN / 1024, 256, 0, stream>>>(din, blks, offs);
    fill_csr<<<EE / 256, 256, 0, stream>>>(src, dst, ew, ro, offs,
                                           (const unsigned short*)repbase_w, rankpack16, edg);

    // 3) conv layer 1: gather x (64 dims), then GEMM + fused GraphNorm1
    cvt_x<<<NN * 64 / 1024, 256, 0, stream>>>(x, xbf);
    transp_cvt<<<dim3(128 / 32, 64 / 32), 256, 0, stream>>>(W1, w1t, 64, 128);
    gather64<<<NN / 4, 256, 0, stream>>>(xbf, offs, edg, aggx);
    conv1_gn<<<NN / 128, 256, 0, stream>>>(aggx, w1t, ri, a1, g1, b1, Bbf);   // Bbf = gn1

    // 4) conv layer 2: GEMM, then wave-per-node gather, then GraphNorm2
    transp_cvt<<<dim3(96 / 32, 128 / 32), 256, 0, stream>>>(W2, w2t, 128, 96);
    conv2_mfma<<<NN / 128, 256, 0, stream>>>(Bbf, w2t, Abf);                  // h2 (xbf/aggx dead)
    gather96<<<NN / 4, 256, 0, stream>>>(Abf, offs, edg, Bbf);                // Bbf = agg2 (gn1 dead)
    graphnorm_k<96><<<BB, 256, 0, stream>>>(Bbf, ri, a2, g2, b2);             // Bbf = gn2 (MLP input)

    // 5) MLP
    transp_cvt<<<dim3(HID / 32, INMLP / 32), 256, 0, stream>>>(Win, WinT, INMLP, HID);
    mlp1_mfma<<<dim3(BB / 128, HID / 128, 2), 256, 0, stream>>>(Bbf, WinT, D0);   // split-K partials
    transp_cvt<<<dim3(HID4 / 32, HID / 32), 256, 0, stream>>>(Whid, WhidT, HID, HID4);
    transp_cvt<<<dim3(OUTF / 32, HID4 / 32), 256, 0, stream>>>(Wcls, WclsT, HID4, OUTF);
    rownorm_hid<<<BB, 256, 0, stream>>>(D0, D1);                                  // D0 = norm(lrelu(D0+D1)) bf16
    mfma_gemm<true, true><<<dim3(BB / 64, HID4 / 64), 256, 0, stream>>>(nullptr, D0, WhidT, Y2, BB, HID4, HID);
    rownorm<HID4><<<BB, 256, 0, stream>>>(Y2);
    mfma_gemm<false, false><<<dim3(BB / 64, OUTF / 64), 256, 0, stream>>>(Y2, nullptr, WclsT, out, BB, OUTF, HID4);
}